// Round 1
// baseline (382.957 us; speedup 1.0000x reference)
//
#include <hip/hip_runtime.h>
#include <hip/hip_fp16.h>

#define SEQ    2048
#define DIN    2048
#define DOUT   2048
#define NH     32
#define NKV    8
#define HD     64
#define BB     2
#define NT_K   32   // K / 64 (K = 2048 for both GEMMs)

typedef _Float16 half_t;
typedef __attribute__((ext_vector_type(8))) _Float16 half8;
typedef __attribute__((ext_vector_type(4))) _Float16 half4;
typedef __attribute__((ext_vector_type(2))) __fp16   fp16x2;
typedef __attribute__((ext_vector_type(4))) float    floatx4;

union H8U { half8 h; int u[4]; };
union H2I { fp16x2 h; int i; };

#if __has_builtin(__builtin_amdgcn_exp2f)
#define EXP2F(x) __builtin_amdgcn_exp2f(x)
#else
#define EXP2F(x) __expf((x) * 0.6931471805599453f)
#endif

// async 16B global->LDS (wave-uniform LDS base + lane*16)
__device__ __forceinline__ void gload16(void* l, const void* g) {
    __builtin_amdgcn_global_load_lds(
        (const __attribute__((address_space(1))) void*)g,
        (__attribute__((address_space(3))) void*)l, 16, 0, 0);
}

// raw barrier pinned against scheduler motion (phase discipline)
__device__ __forceinline__ void phase_bar() {
    __builtin_amdgcn_sched_barrier(0);
    __builtin_amdgcn_s_barrier();
    __builtin_amdgcn_sched_barrier(0);
}
// rule #18: sched_barrier(0) immediately after inline-asm waitcnt
#define LGKM0() do { asm volatile("s_waitcnt lgkmcnt(0)" ::: "memory"); \
                     __builtin_amdgcn_sched_barrier(0); } while (0)
#define VMW(n)  do { asm volatile("s_waitcnt vmcnt(" #n ")" ::: "memory"); \
                     __builtin_amdgcn_sched_barrier(0); } while (0)

// ---------------------------------------------------------------- cast f32->f16
__global__ void cast_f2h(const float* __restrict__ in, half_t* __restrict__ out, int n4) {
    int i = blockIdx.x * blockDim.x + threadIdx.x;
    if (i < n4) {
        float4 v = ((const float4*)in)[i];
        half4 h;
        h[0] = (half_t)v.x; h[1] = (half_t)v.y; h[2] = (half_t)v.z; h[3] = (half_t)v.w;
        ((half4*)out)[i] = h;
    }
}

// ---------------------------------------------------------------- transpose+cast: f32 [Kd][Nd] -> f16 [Nd][Kd]
__global__ __launch_bounds__(256) void tcast(const float* __restrict__ in, half_t* __restrict__ out,
                                             int Kd, int Nd) {
    __shared__ float T[32][33];
    int x0 = blockIdx.x * 32, y0 = blockIdx.y * 32;
    int tx = threadIdx.x & 31, ty = threadIdx.x >> 5;
    #pragma unroll
    for (int j = 0; j < 4; j++)
        T[ty + j * 8][tx] = in[(size_t)(y0 + ty + j * 8) * Nd + x0 + tx];
    __syncthreads();
    #pragma unroll
    for (int j = 0; j < 4; j++)
        out[(size_t)(x0 + ty + j * 8) * Kd + y0 + tx] = (half_t)T[tx][ty + j * 8];
}

// ================================================================ 256x256 / BK=64 / 8-wave / 8-phase GEMM core
// Tiles: A,B = [256 rows][64 k] f16, double-buffered (128 KiB LDS total).
// LDS layout per tile: 2 k-subblocks of [128 pair-rows][8 slots][8 halves],
//   slot = ((row&1)*4 + kq) ^ (pairrow&7)  (bank-conflict-free, measured 0 conflicts).
// Wave (of 8): wr=wave>>2 owns 128 rows, wc=wave&3 owns 64 cols -> acc[8][4].
// Per K-tile: 4 phases x 16 MFMA. P0: read A-quad0(8)+B-half0(4); P1: B-half1(4);
// P2: A-quad1(8); P3: zero ds_reads -> stage tile T+2 into buf[T&1] (just released),
// then vmcnt(8): tile T+1's 8 loads verified landed, tile T+2's 8 stay in flight.
__device__ __forceinline__ void gemm256_core(
    const half_t* __restrict__ A, const half_t* __restrict__ Bt,
    int m0, int n0, half_t* As, half_t* Bs, floatx4 (&acc)[8][4])
{
    const int tid  = threadIdx.x;
    const int wave = tid >> 6, lane = tid & 63;
    const int quad = lane >> 4, l15 = lane & 15;
    const int wr128 = (wave >> 2) * 128, wc64 = (wave & 3) * 64;
    const int K = DIN;

    // staging: per-thread pre-swizzled global sources, linear LDS dests
    const half_t* pa[4]; const half_t* pb[4]; int ldso[4];
    #pragma unroll
    for (int is = 0; is < 4; is++) {
        int s  = is * 512 + tid;
        int kb = s >> 10, s1 = s & 1023;
        int p  = s1 >> 3, c = (s1 & 7) ^ (p & 7);
        int row  = 2 * p + (c >> 2);
        int koff = kb * 32 + (c & 3) * 8;
        pa[is] = A  + (size_t)(m0 + row) * K + koff;
        pb[is] = Bt + (size_t)(n0 + row) * K + koff;
        ldso[is] = (is * 512 + wave * 64) * 8;
    }
    // LDS fragment read offsets (halves), k-sub term (+8192) added at use
    int aoff[8], boff[4];
    #pragma unroll
    for (int m = 0; m < 8; m++) {
        int r = wr128 + m * 16 + l15, p = r >> 1;
        aoff[m] = p * 64 + ((((r & 1) * 4 + quad) ^ (p & 7)) * 8);
    }
    #pragma unroll
    for (int n = 0; n < 4; n++) {
        int r = wc64 + n * 16 + l15, p = r >> 1;
        boff[n] = p * 64 + ((((r & 1) * 4 + quad) ^ (p & 7)) * 8);
    }

    // prologue: stage tile 0 -> buf0, tile 1 -> buf1 (16 loads), land tile 0
    #pragma unroll
    for (int is = 0; is < 4; is++) {
        gload16(As + ldso[is], pa[is]);
        gload16(Bs + ldso[is], pb[is]);
    }
    #pragma unroll
    for (int is = 0; is < 4; is++) {
        gload16(As + 16384 + ldso[is], pa[is] + 64);
        gload16(Bs + 16384 + ldso[is], pb[is] + 64);
    }
    VMW(8);
    phase_bar();

    half8 af[4][2], bf[4][2];
    for (int T = 0; T < NT_K; T++) {
        half_t* cA = As + (T & 1) * 16384;
        half_t* cB = Bs + (T & 1) * 16384;

        // ---- P0: A-quad0 (8 reads) + B-half0 (4 reads); MFMA m0-3 x n0-1
        #pragma unroll
        for (int mi = 0; mi < 4; mi++) {
            af[mi][0] = *(const half8*)(cA + aoff[mi]);
            af[mi][1] = *(const half8*)(cA + 8192 + aoff[mi]);
        }
        #pragma unroll
        for (int ni = 0; ni < 2; ni++) {
            bf[ni][0] = *(const half8*)(cB + boff[ni]);
            bf[ni][1] = *(const half8*)(cB + 8192 + boff[ni]);
        }
        phase_bar();
        LGKM0();
        __builtin_amdgcn_s_setprio(1);
        #pragma unroll
        for (int ni = 0; ni < 2; ni++)
            #pragma unroll
            for (int mi = 0; mi < 4; mi++)
                #pragma unroll
                for (int ks = 0; ks < 2; ks++)
                    acc[mi][ni] = __builtin_amdgcn_mfma_f32_16x16x32_f16(af[mi][ks], bf[ni][ks], acc[mi][ni], 0, 0, 0);
        __builtin_amdgcn_s_setprio(0);
        phase_bar();

        // ---- P1: B-half1 (4 reads); MFMA m0-3 x n2-3
        #pragma unroll
        for (int ni = 2; ni < 4; ni++) {
            bf[ni][0] = *(const half8*)(cB + boff[ni]);
            bf[ni][1] = *(const half8*)(cB + 8192 + boff[ni]);
        }
        phase_bar();
        LGKM0();
        __builtin_amdgcn_s_setprio(1);
        #pragma unroll
        for (int ni = 2; ni < 4; ni++)
            #pragma unroll
            for (int mi = 0; mi < 4; mi++)
                #pragma unroll
                for (int ks = 0; ks < 2; ks++)
                    acc[mi][ni] = __builtin_amdgcn_mfma_f32_16x16x32_f16(af[mi][ks], bf[ni][ks], acc[mi][ni], 0, 0, 0);
        __builtin_amdgcn_s_setprio(0);
        phase_bar();

        // ---- P2: A-quad1 (8 reads); MFMA m4-7 x n0-1 (bf[0..1] held from P0)
        #pragma unroll
        for (int mi = 0; mi < 4; mi++) {
            af[mi][0] = *(const half8*)(cA + aoff[4 + mi]);
            af[mi][1] = *(const half8*)(cA + 8192 + aoff[4 + mi]);
        }
        phase_bar();
        LGKM0();
        __builtin_amdgcn_s_setprio(1);
        #pragma unroll
        for (int ni = 0; ni < 2; ni++)
            #pragma unroll
            for (int mi = 0; mi < 4; mi++)
                #pragma unroll
                for (int ks = 0; ks < 2; ks++)
                    acc[4 + mi][ni] = __builtin_amdgcn_mfma_f32_16x16x32_f16(af[mi][ks], bf[ni][ks], acc[4 + mi][ni], 0, 0, 0);
        __builtin_amdgcn_s_setprio(0);
        phase_bar();

        // ---- P3: no ds_reads -> stage tile T+2 into this (released) buffer;
        //          MFMA m4-7 x n2-3; counted vmcnt (never 0 in steady state)
        if (T + 2 < NT_K) {
            const int kk = (T + 2) * 64;
            #pragma unroll
            for (int is = 0; is < 4; is++) {
                gload16(cA + ldso[is], pa[is] + kk);
                gload16(cB + ldso[is], pb[is] + kk);
            }
            __builtin_amdgcn_s_setprio(1);
            #pragma unroll
            for (int ni = 2; ni < 4; ni++)
                #pragma unroll
                for (int mi = 0; mi < 4; mi++)
                    #pragma unroll
                    for (int ks = 0; ks < 2; ks++)
                        acc[4 + mi][ni] = __builtin_amdgcn_mfma_f32_16x16x32_f16(af[mi][ks], bf[ni][ks], acc[4 + mi][ni], 0, 0, 0);
            __builtin_amdgcn_s_setprio(0);
            VMW(8);
        } else {
            __builtin_amdgcn_s_setprio(1);
            #pragma unroll
            for (int ni = 2; ni < 4; ni++)
                #pragma unroll
                for (int mi = 0; mi < 4; mi++)
                    #pragma unroll
                    for (int ks = 0; ks < 2; ks++)
                        acc[4 + mi][ni] = __builtin_amdgcn_mfma_f32_16x16x32_f16(af[mi][ks], bf[ni][ks], acc[4 + mi][ni], 0, 0, 0);
            __builtin_amdgcn_s_setprio(0);
            VMW(0);   // tail: no new loads issued, must drain to land tile T+1
        }
        phase_bar();
    }
}

// ---------------------------------------------------------------- fused QKV GEMM + K-RoPE + relayout (256^2 8-phase)
// C = xh[4096x2048] @ WqkvT[3072x2048]^T ; each wave's 64-col span = one head:
//   cols <2048  : plain store -> Qh [b][h][s][64]
//   2048..2559  : RoPE        -> Kh [b][g][s][64]
//   2560..3071  : transpose   -> Vt [b][g][d][SEQ]
__global__ __launch_bounds__(512, 2) void gemm_qkv(
    const half_t* __restrict__ A, const half_t* __restrict__ Bt,
    const float* __restrict__ cosb, const float* __restrict__ sinb,
    half_t* __restrict__ Qh, half_t* __restrict__ Kh, half_t* __restrict__ Vt)
{
    __shared__ half_t As[2][16384];
    __shared__ half_t Bs[2][16384];
    const int m0 = blockIdx.y * 256, n0 = blockIdx.x * 256;

    floatx4 acc[8][4] = {};
    gemm256_core(A, Bt, m0, n0, &As[0][0], &Bs[0][0], acc);

    const int tid = threadIdx.x, wave = tid >> 6, lane = tid & 63;
    const int quad = lane >> 4, l15 = lane & 15;
    const int wr128 = (wave >> 2) * 128, wc64 = (wave & 3) * 64;
    const int headg = (n0 + wc64) >> 6;        // 0..47
    const int b = m0 >> 11;                    // 256-row block never straddles batch
    const int s_base = (m0 & 2047) + wr128 + quad * 4;

    if (headg < 32) {                          // Q: plain head-major store
        half_t* outp = Qh + (size_t)(b * NH + headg) * SEQ * 64;
        #pragma unroll
        for (int m = 0; m < 8; m++)
            #pragma unroll
            for (int n = 0; n < 4; n++) {
                int d = n * 16 + l15;
                #pragma unroll
                for (int r = 0; r < 4; r++)
                    outp[(size_t)(s_base + m * 16 + r) * 64 + d] = (half_t)acc[m][n][r];
            }
    } else if (headg < 40) {                   // K: RoPE
        half_t* outp = Kh + (size_t)(b * NKV + (headg - 32)) * SEQ * 64;
        #pragma unroll
        for (int m = 0; m < 8; m++)
            #pragma unroll
            for (int r = 0; r < 4; r++) {
                int s = s_base + m * 16 + r;
                #pragma unroll
                for (int j = 0; j < 2; j++) {
                    int d = j * 16 + l15;
                    float x1 = acc[m][j][r], x2 = acc[m][j + 2][r];
                    float c1 = cosb[s * 64 + d],      s1 = sinb[s * 64 + d];
                    float c2 = cosb[s * 64 + d + 32], s2 = sinb[s * 64 + d + 32];
                    outp[(size_t)s * 64 + d]      = (half_t)(x1 * c1 - x2 * s1);
                    outp[(size_t)s * 64 + d + 32] = (half_t)(x2 * c2 + x1 * s2);
                }
            }
    } else {                                   // V: transpose to [d][s]
        half_t* vtp = Vt + (size_t)(b * NKV + (headg - 40)) * 64 * SEQ;
        #pragma unroll
        for (int m = 0; m < 8; m++) {
            int s = s_base + m * 16;
            #pragma unroll
            for (int n = 0; n < 4; n++) {
                int d = n * 16 + l15;
                half4 hv;
                hv[0] = (half_t)acc[m][n][0];
                hv[1] = (half_t)acc[m][n][1];
                hv[2] = (half_t)acc[m][n][2];
                hv[3] = (half_t)acc[m][n][3];
                *(half4*)(vtp + (size_t)d * SEQ + s) = hv;
            }
        }
    }
}

// ---------------------------------------------------------------- output projection (256^2 8-phase), f32 out
__global__ __launch_bounds__(512, 2) void gemm_tn_f(
    const half_t* __restrict__ A, const half_t* __restrict__ Bt,
    float* __restrict__ C)
{
    __shared__ half_t As[2][16384];
    __shared__ half_t Bs[2][16384];
    const int m0 = blockIdx.y * 256, n0 = blockIdx.x * 256;

    floatx4 acc[8][4] = {};
    gemm256_core(A, Bt, m0, n0, &As[0][0], &Bs[0][0], acc);

    const int tid = threadIdx.x, wave = tid >> 6, lane = tid & 63;
    const int quad = lane >> 4, l15 = lane & 15;
    const int wr128 = (wave >> 2) * 128, wc64 = (wave & 3) * 64;
    #pragma unroll
    for (int m = 0; m < 8; m++) {
        int row = m0 + wr128 + m * 16 + quad * 4;
        #pragma unroll
        for (int n = 0; n < 4; n++) {
            int col = n0 + wc64 + n * 16 + l15;
            #pragma unroll
            for (int r = 0; r < 4; r++)
                C[(size_t)(row + r) * DOUT + col] = acc[m][n][r];
        }
    }
}

// ---------------------------------------------------------------- causal GQA flash attention (S^T layout) — unchanged
__global__ __launch_bounds__(256, 4) void attn(
    const half_t* __restrict__ Qh, const half_t* __restrict__ Kh,
    const half_t* __restrict__ Vt, const float* __restrict__ cosb,
    const float* __restrict__ sinb, half_t* __restrict__ ctx)
{
    __shared__ half_t Ks[2][4096];
    __shared__ half_t Vs[2][4096];

    const int tid = threadIdx.x, wave = tid >> 6, lane = tid & 63;
    const int quad = lane >> 4, l15 = lane & 15;
    const int bid = blockIdx.x;
    const int k  = bid >> 8;
    const int u  = bid & 255;
    const int q2 = u & 3;
    const int bh = u >> 2;
    const int qt = (k == 0) ? 15 - 2 * q2 : (k == 1) ? 2 * q2
                 : (k == 2) ? 14 - 2 * q2 : 2 * q2 + 1;
    const int b  = bh >> 5;
    const int h  = bh & 31;
    const int g  = h >> 2;
    const int q0 = qt * 128;
    const int wm = wave * 32;

    const half_t* kp = Kh + (size_t)(b * NKV + g) * SEQ * 64;
    const half_t* vp = Vt + (size_t)(b * NKV + g) * 64 * SEQ;

    half8 qf[2][2];
    {
        const float sc = 0.125f * 1.44269504088896f;
        const half_t* qpp = Qh + ((size_t)(b * NH + h) * SEQ + q0 + wm) * 64;
        #pragma unroll
        for (int mf = 0; mf < 2; mf++) {
            int s = q0 + wm + mf * 16 + l15;
            const float* cp = cosb + s * 64 + quad * 8;
            const float* sp = sinb + s * 64 + quad * 8;
            half8 xa = *(const half8*)(qpp + (size_t)(mf * 16 + l15) * 64 + quad * 8);
            half8 xb = *(const half8*)(qpp + (size_t)(mf * 16 + l15) * 64 + 32 + quad * 8);
            float4 c1a = *(const float4*)(cp),      c1b = *(const float4*)(cp + 4);
            float4 s1a = *(const float4*)(sp),      s1b = *(const float4*)(sp + 4);
            float4 c2a = *(const float4*)(cp + 32), c2b = *(const float4*)(cp + 36);
            float4 s2a = *(const float4*)(sp + 32), s2b = *(const float4*)(sp + 36);
            #pragma unroll
            for (int t = 0; t < 8; t++) {
                float cc1 = (t < 4) ? ((const float*)&c1a)[t] : ((const float*)&c1b)[t - 4];
                float ss1 = (t < 4) ? ((const float*)&s1a)[t] : ((const float*)&s1b)[t - 4];
                float cc2 = (t < 4) ? ((const float*)&c2a)[t] : ((const float*)&c2b)[t - 4];
                float ss2 = (t < 4) ? ((const float*)&s2a)[t] : ((const float*)&s2b)[t - 4];
                float x1 = (float)xa[t], x2 = (float)xb[t];
                qf[mf][0][t] = (half_t)((x1 * cc1 - x2 * ss1) * sc);
                qf[mf][1][t] = (half_t)((x2 * cc2 + x1 * ss2) * sc);
            }
        }
    }

    int koff[2], voff[2], lo[2];
    #pragma unroll
    for (int is = 0; is < 2; is++) {
        int s = is * 256 + tid;
        int p = s >> 3, c = (s & 7) ^ (p & 7);
        koff[is] = p * 64 + c * 8;
        voff[is] = p * SEQ + c * 8;
        lo[is]   = (is * 256 + wave * 64) * 8;
    }

    float m_i[2], l_i[2];
    m_i[0] = m_i[1] = -__builtin_inff();
    l_i[0] = l_i[1] = 0.f;
    floatx4 o[2][4] = {};

    const int ntiles = 2 * qt + 2;
    #pragma unroll
    for (int is = 0; is < 2; is++) {
        gload16(&Ks[0][lo[is]], kp + koff[is]);
        gload16(&Vs[0][lo[is]], vp + voff[is]);
    }

    const int srcA = l15 + ((quad & 1) ? 32 : 0);
    const int srcB = srcA + 16;
    const bool hiK = (quad >> 1) != 0;

    for (int kt = 0; kt < ntiles; kt++) {
        const int cur = kt & 1;
        const int kb  = kt * 64;
        __syncthreads();
        if (kt + 1 < ntiles) {
            const int kb2 = (kt + 1) * 64;
            #pragma unroll
            for (int is = 0; is < 2; is++) {
                gload16(&Ks[cur ^ 1][lo[is]], kp + (size_t)kb2 * 64 + koff[is]);
                gload16(&Vs[cur ^ 1][lo[is]], vp + kb2 + voff[is]);
            }
        }

        if (kb <= q0 + wm + 31) {
            floatx4 sa[2][4] = {};
            #pragma unroll
            for (int kc = 0; kc < 2; kc++)
                #pragma unroll
                for (int kf = 0; kf < 4; kf++) {
                    int row = kf * 16 + l15;
                    int sc = ((kc * 4 + quad) ^ (row & 7));
                    half8 kfr = *(const half8*)&Ks[cur][row * 64 + sc * 8];
                    sa[0][kf] = __builtin_amdgcn_mfma_f32_16x16x32_f16(kfr, qf[0][kc], sa[0][kf], 0, 0, 0);
                    sa[1][kf] = __builtin_amdgcn_mfma_f32_16x16x32_f16(kfr, qf[1][kc], sa[1][kf], 0, 0, 0);
                }

            if (kb + 63 > q0 + wm) {
                #pragma unroll
                for (int kf = 0; kf < 4; kf++)
                    #pragma unroll
                    for (int r = 0; r < 4; r++) {
                        int key = kb + kf * 16 + quad * 4 + r;
                        if (key > q0 + wm + l15)      sa[0][kf][r] = -__builtin_inff();
                        if (key > q0 + wm + 16 + l15) sa[1][kf][r] = -__builtin_inff();
                    }
            }

            int eh[2][4][2];
            float alpha[2];
            #pragma unroll
            for (int mf = 0; mf < 2; mf++) {
                float mt = sa[mf][0][0];
                #pragma unroll
                for (int kf = 0; kf < 4; kf++)
                    #pragma unroll
                    for (int r = 0; r < 4; r++) mt = fmaxf(mt, sa[mf][kf][r]);
                mt = fmaxf(mt, __shfl_xor(mt, 16));
                mt = fmaxf(mt, __shfl_xor(mt, 32));
                float mn = fmaxf(m_i[mf], mt);
                alpha[mf] = EXP2F(m_i[mf] - mn);
                m_i[mf] = mn;
                float rs = 0.f;
                #pragma unroll
                for (int kf = 0; kf < 4; kf++) {
                    float e0 = EXP2F(sa[mf][kf][0] - mn);
                    float e1 = EXP2F(sa[mf][kf][1] - mn);
                    float e2 = EXP2F(sa[mf][kf][2] - mn);
                    float e3 = EXP2F(sa[mf][kf][3] - mn);
                    rs += (e0 + e1) + (e2 + e3);
                    H2I p01, p23;
                    p01.h = __builtin_amdgcn_cvt_pkrtz(e0, e1);
                    p23.h = __builtin_amdgcn_cvt_pkrtz(e2, e3);
                    eh[mf][kf][0] = p01.i;
                    eh[mf][kf][1] = p23.i;
                }
                rs += __shfl_xor(rs, 16);
                rs += __shfl_xor(rs, 32);
                l_i[mf] = l_i[mf] * alpha[mf] + rs;
                #pragma unroll
                for (int nf = 0; nf < 4; nf++)
                    #pragma unroll
                    for (int r = 0; r < 4; r++) o[mf][nf][r] *= alpha[mf];
            }

            #pragma unroll
            for (int kc = 0; kc < 2; kc++) {
                H8U pf[2];
                #pragma unroll
                for (int mf = 0; mf < 2; mf++) {
                    int a0 = __shfl(eh[mf][2 * kc][0],     srcA);
                    int a1 = __shfl(eh[mf][2 * kc][1],     srcA);
                    int b0 = __shfl(eh[mf][2 * kc + 1][0], srcA);
                    int b1 = __shfl(eh[mf][2 * kc + 1][1], srcA);
                    int c0 = __shfl(eh[mf][2 * kc][0],     srcB);
                    int c1 = __shfl(eh[mf][2 * kc][1],     srcB);
                    int d0 = __shfl(eh[mf][2 * kc + 1][0], srcB);
                    int d1 = __shfl(eh[mf][2 * kc + 1][1], srcB);
                    pf[mf].u[0] = hiK ? b0 : a0;
                    pf[mf].u[1] = hiK ? b1 : a1;
                    pf[mf].u[2] = hiK ? d0 : c0;
                    pf[mf].u[3] = hiK ? d1 : c1;
                }
                #pragma unroll
                for (int nf = 0; nf < 4; nf++) {
                    int row = nf * 16 + l15;
                    int sc = ((kc * 4 + quad) ^ (row & 7));
                    half8 vf = *(const half8*)&Vs[cur][row * 64 + sc * 8];
                    o[0][nf] = __builtin_amdgcn_mfma_f32_16x16x32_f16(vf, pf[0].h, o[0][nf], 0, 0, 0);
                    o[1][nf] = __builtin_amdgcn_mfma_f32_16x16x32_f16(vf, pf[1].h, o[1][nf], 0, 0, 0);
                }
            }
        }
    }

    #pragma unroll
    for (int mf = 0; mf < 2; mf++) {
        float inv = 1.0f / l_i[mf];
        int s = q0 + wm + mf * 16 + l15;
        half_t* op = ctx + (size_t)(b * SEQ + s) * DOUT + h * 64 + quad * 4;
        #pragma unroll
        for (int nf = 0; nf < 4; nf++) {
            half4 hv;
            hv[0] = (half_t)(o[mf][nf][0] * inv);
            hv[1] = (half_t)(o[mf][nf][1] * inv);
            hv[2] = (half_t)(o[mf][nf][2] * inv);
            hv[3] = (half_t)(o[mf][nf][3] * inv);
            *(half4*)(op + nf * 16) = hv;
        }
    }
}

// ---------------------------------------------------------------- launch
extern "C" void kernel_launch(void* const* d_in, const int* in_sizes, int n_in,
                              void* d_out, int out_size, void* d_ws, size_t ws_size,
                              hipStream_t stream) {
    const float* x    = (const float*)d_in[0];
    const float* cosb = (const float*)d_in[1];
    const float* sinb = (const float*)d_in[2];
    const float* Wq   = (const float*)d_in[4];
    const float* Wk   = (const float*)d_in[5];
    const float* Wv   = (const float*)d_in[6];
    const float* Wo   = (const float*)d_in[7];
    float* out = (float*)d_out;

    const size_t M  = (size_t)BB * SEQ;   // 4096
    const size_t nX = M * DIN;

    char* ws = (char*)d_ws;
    const size_t MB = 1048576;
    half_t* xh     = (half_t*)(ws);              // 16 MiB
    half_t* WqkvT  = (half_t*)(ws + 16 * MB);    // 12 MiB  [3072][2048]
    half_t* WoT    = (half_t*)(ws + 28 * MB);    //  8 MiB
    half_t* Qh     = (half_t*)(ws + 36 * MB);    // 16 MiB  [b][h][s][64] (raw, pre-RoPE)
    half_t* Kh     = (half_t*)(ws + 52 * MB);    //  4 MiB  [b][g][s][64] (RoPE'd)
    half_t* Vt     = (half_t*)(ws + 56 * MB);    //  4 MiB  [b][g][d][SEQ]
    half_t* ctxh   = (half_t*)(ws + 60 * MB);    // 16 MiB  [b][s][h*64]

    cast_f2h<<<(nX / 4) / 256, 256, 0, stream>>>(x, xh, nX / 4);
    tcast<<<dim3(64, 64), 256, 0, stream>>>(Wq, WqkvT, DIN, DOUT);
    tcast<<<dim3(16, 64), 256, 0, stream>>>(Wk, WqkvT + (size_t)2048 * 2048, DIN, 512);
    tcast<<<dim3(16, 64), 256, 0, stream>>>(Wv, WqkvT + (size_t)2560 * 2048, DIN, 512);
    tcast<<<dim3(64, 64), 256, 0, stream>>>(Wo, WoT, DOUT, DOUT);

    // fused QKV projection + K-RoPE + relayout (256^2 8-phase, 12x16 = 192 blocks)
    gemm_qkv<<<dim3(3072 / 256, M / 256), 512, 0, stream>>>(xh, WqkvT, cosb, sinb, Qh, Kh, Vt);

    // attention (Q-RoPE fused at load)
    attn<<<BB * NH * (SEQ / 128), 256, 0, stream>>>(Qh, Kh, Vt, cosb, sinb, ctxh);

    // output projection (256^2 8-phase, 8x16 = 128 blocks)
    gemm_tn_f<<<dim3(DOUT / 256, M / 256), 512, 0, stream>>>(ctxh, WoT, out);
}

// Round 2
// 354.559 us; speedup vs baseline: 1.0801x; 1.0801x over previous
//
#include <hip/hip_runtime.h>
#include <hip/hip_fp16.h>

#define SEQ    2048
#define DIN    2048
#define DOUT   2048
#define NH     32
#define NKV    8
#define HD     64
#define BB     2
#define NT_K   32   // K / 64 (K = 2048 for both GEMMs)

typedef _Float16 half_t;
typedef __attribute__((ext_vector_type(8))) _Float16 half8;
typedef __attribute__((ext_vector_type(4))) _Float16 half4;
typedef __attribute__((ext_vector_type(2))) __fp16   fp16x2;
typedef __attribute__((ext_vector_type(4))) float    floatx4;

union H8U { half8 h; int u[4]; };
union H2I { fp16x2 h; int i; };

#if __has_builtin(__builtin_amdgcn_exp2f)
#define EXP2F(x) __builtin_amdgcn_exp2f(x)
#else
#define EXP2F(x) __expf((x) * 0.6931471805599453f)
#endif

// async 16B global->LDS (wave-uniform LDS base + lane*16)
__device__ __forceinline__ void gload16(void* l, const void* g) {
    __builtin_amdgcn_global_load_lds(
        (const __attribute__((address_space(1))) void*)g,
        (__attribute__((address_space(3))) void*)l, 16, 0, 0);
}

// m201 template discipline: raw barrier, advisory lgkm drain, counted vmcnt.
// NO sched_barrier(0) anywhere (m141: order-pinning = 510 TF regression).
#define BAR()   __builtin_amdgcn_s_barrier()
#define LGKM0() asm volatile("s_waitcnt lgkmcnt(0)")
#define VMW2()  asm volatile("s_waitcnt vmcnt(2)" ::: "memory")
#define VMW0()  asm volatile("s_waitcnt vmcnt(0)" ::: "memory")

// ---------------------------------------------------------------- cast f32->f16
__global__ void cast_f2h(const float* __restrict__ in, half_t* __restrict__ out, int n4) {
    int i = blockIdx.x * blockDim.x + threadIdx.x;
    if (i < n4) {
        float4 v = ((const float4*)in)[i];
        half4 h;
        h[0] = (half_t)v.x; h[1] = (half_t)v.y; h[2] = (half_t)v.z; h[3] = (half_t)v.w;
        ((half4*)out)[i] = h;
    }
}

// ---------------------------------------------------------------- transpose+cast: f32 [Kd][Nd] -> f16 [Nd][Kd]
__global__ __launch_bounds__(256) void tcast(const float* __restrict__ in, half_t* __restrict__ out,
                                             int Kd, int Nd) {
    __shared__ float T[32][33];
    int x0 = blockIdx.x * 32, y0 = blockIdx.y * 32;
    int tx = threadIdx.x & 31, ty = threadIdx.x >> 5;
    #pragma unroll
    for (int j = 0; j < 4; j++)
        T[ty + j * 8][tx] = in[(size_t)(y0 + ty + j * 8) * Nd + x0 + tx];
    __syncthreads();
    #pragma unroll
    for (int j = 0; j < 4; j++)
        out[(size_t)(x0 + ty + j * 8) * Kd + y0 + tx] = (half_t)T[tx][ty + j * 8];
}

// ================================================================ 256x256 / BK=64 / 8-wave GEMM core
// Faithful m201 schedule: 8 phases per 2 K-tiles (ph0-3 read buf0/tile 2i,
// ph4-7 read buf1/tile 2i+1). One half-tile (2 gloads) staged per phase:
//   ph0-2: tile 2i+1 ht1-3 -> buf1   (buf1 reads ended prev iter ph6)
//   ph3-6: tile 2i+2 ht0-3 -> buf0   (buf0 reads end ph2)
//   ph7  : tile 2i+3 ht0   -> buf1
// vmcnt(2) only at end of ph3 and ph7: lands the 8 oldest = next tile's 4
// half-tiles; 1 half-tile (2 loads) always stays in flight. Tail peeled, vmcnt(0).
// Phase body: { ds_reads ; stage ; s_barrier ; lgkmcnt(0) ; setprio(1) ;
//               16 MFMA ; setprio(0) ; s_barrier }  -- no sched_barrier.
#define DS_AQ(Q) \
    _Pragma("unroll") \
    for (int mi = 0; mi < 4; mi++) { \
        af[mi][0] = *(const half8*)(cA + aoff[(Q) + mi]); \
        af[mi][1] = *(const half8*)(cA + 8192 + aoff[(Q) + mi]); \
    }
#define DS_BH(N0, N1) \
    _Pragma("unroll") \
    for (int ni = (N0); ni < (N1); ni++) { \
        bf[ni][0] = *(const half8*)(cB + boff[ni]); \
        bf[ni][1] = *(const half8*)(cB + 8192 + boff[ni]); \
    }
#define MFMA_Q(MI0, NI0) \
    __builtin_amdgcn_s_setprio(1); \
    _Pragma("unroll") \
    for (int ni = 0; ni < 2; ni++) \
        _Pragma("unroll") \
        for (int mi = 0; mi < 4; mi++) \
            _Pragma("unroll") \
            for (int ks = 0; ks < 2; ks++) \
                acc[(MI0) + mi][(NI0) + ni] = __builtin_amdgcn_mfma_f32_16x16x32_f16( \
                    af[mi][ks], bf[(NI0) + ni][ks], acc[(MI0) + mi][(NI0) + ni], 0, 0, 0); \
    __builtin_amdgcn_s_setprio(0);

// 4 phases covering one K-tile; STG0..STG3 = one stage slot per phase; VMW_ at end
#define PH_GROUP(STG0, STG1, STG2, STG3, VMW_) \
    DS_AQ(0); DS_BH(0, 2); STG0; BAR(); LGKM0(); MFMA_Q(0, 0); BAR(); \
    DS_BH(2, 4);           STG1; BAR(); LGKM0(); MFMA_Q(0, 2); BAR(); \
    DS_AQ(4);              STG2; BAR(); LGKM0(); MFMA_Q(4, 0); BAR(); \
    STG3; MFMA_Q(4, 2); VMW_; BAR();

__device__ __forceinline__ void gemm256_core(
    const half_t* __restrict__ A, const half_t* __restrict__ Bt,
    int m0, int n0, half_t* AsB, half_t* BsB, floatx4 (&acc)[8][4])
{
    const int tid  = threadIdx.x;
    const int wave = tid >> 6, lane = tid & 63;
    const int quad = lane >> 4, l15 = lane & 15;
    const int wr128 = (wave >> 2) * 128, wc64 = (wave & 3) * 64;
    const int K = DIN;

    // staging: per-thread pre-swizzled global sources, linear LDS dests
    const half_t* pa[4]; const half_t* pb[4]; int ldso[4];
    #pragma unroll
    for (int is = 0; is < 4; is++) {
        int s  = is * 512 + tid;
        int kb = s >> 10, s1 = s & 1023;
        int p  = s1 >> 3, c = (s1 & 7) ^ (p & 7);
        int row  = 2 * p + (c >> 2);
        int koff = kb * 32 + (c & 3) * 8;
        pa[is] = A  + (size_t)(m0 + row) * K + koff;
        pb[is] = Bt + (size_t)(n0 + row) * K + koff;
        ldso[is] = (is * 512 + wave * 64) * 8;
    }
    // LDS fragment read offsets (halves); +8192 for k-subblock 1
    int aoff[8], boff[4];
    #pragma unroll
    for (int m = 0; m < 8; m++) {
        int r = wr128 + m * 16 + l15, p = r >> 1;
        aoff[m] = p * 64 + ((((r & 1) * 4 + quad) ^ (p & 7)) * 8);
    }
    #pragma unroll
    for (int n = 0; n < 4; n++) {
        int r = wc64 + n * 16 + l15, p = r >> 1;
        boff[n] = p * 64 + ((((r & 1) * 4 + quad) ^ (p & 7)) * 8);
    }

    // half-tile stage: ht 0=A-ksub0, 1=A-ksub1, 2=B-ksub0, 3=B-ksub1 (2 gloads each)
    auto stage = [&](int tile, int ht) {
        const int kk = tile * 64;
        half_t* dst = (ht < 2 ? AsB : BsB) + (tile & 1) * 16384;
        const int i0 = (ht & 1) * 2;
        if (ht < 2) {
            gload16(dst + ldso[i0],     pa[i0] + kk);
            gload16(dst + ldso[i0 + 1], pa[i0 + 1] + kk);
        } else {
            gload16(dst + ldso[i0],     pb[i0] + kk);
            gload16(dst + ldso[i0 + 1], pb[i0 + 1] + kk);
        }
    };

    // prologue: tile0 fully staged + tile1 ht0 in flight
    stage(0, 0); stage(0, 1); stage(0, 2); stage(0, 3);
    stage(1, 0);
    VMW2();           // 10 outstanding -> land 8 oldest = tile0
    BAR();

    half8 af[4][2], bf[4][2];
    #pragma unroll 1
    for (int i = 0; i < NT_K / 2 - 1; i++) {
        const int t0 = 2 * i;
        {   // tile t0 in buf0
            const half_t* cA = AsB; const half_t* cB = BsB;
            PH_GROUP(stage(t0 + 1, 1), stage(t0 + 1, 2), stage(t0 + 1, 3),
                     stage(t0 + 2, 0), VMW2());
        }
        {   // tile t0+1 in buf1
            const half_t* cA = AsB + 16384; const half_t* cB = BsB + 16384;
            PH_GROUP(stage(t0 + 2, 1), stage(t0 + 2, 2), stage(t0 + 2, 3),
                     stage(t0 + 3, 0), VMW2());
        }
    }
    // tail: tiles NT_K-2 (buf0), NT_K-1 (buf1)
    {
        const half_t* cA = AsB; const half_t* cB = BsB;
        PH_GROUP(stage(NT_K - 1, 1), stage(NT_K - 1, 2), stage(NT_K - 1, 3),
                 (void)0, VMW0());
    }
    {
        const half_t* cA = AsB + 16384; const half_t* cB = BsB + 16384;
        PH_GROUP((void)0, (void)0, (void)0, (void)0, (void)0);
    }
}

// ---------------------------------------------------------------- fused QKV GEMM + K-RoPE + relayout
// C = xh[4096x2048] @ WqkvT[3072x2048]^T ; each wave's 64-col span = one head:
//   cols <2048  : plain store -> Qh [b][h][s][64]
//   2048..2559  : RoPE        -> Kh [b][g][s][64]
//   2560..3071  : transpose   -> Vt [b][g][d][SEQ]
__global__ __launch_bounds__(512, 2) void gemm_qkv(
    const half_t* __restrict__ A, const half_t* __restrict__ Bt,
    const float* __restrict__ cosb, const float* __restrict__ sinb,
    half_t* __restrict__ Qh, half_t* __restrict__ Kh, half_t* __restrict__ Vt)
{
    __shared__ half_t As[2][16384];
    __shared__ half_t Bs[2][16384];
    const int m0 = blockIdx.y * 256, n0 = blockIdx.x * 256;

    floatx4 acc[8][4] = {};
    gemm256_core(A, Bt, m0, n0, &As[0][0], &Bs[0][0], acc);

    const int tid = threadIdx.x, wave = tid >> 6, lane = tid & 63;
    const int quad = lane >> 4, l15 = lane & 15;
    const int wr128 = (wave >> 2) * 128, wc64 = (wave & 3) * 64;
    const int headg = (n0 + wc64) >> 6;        // 0..47
    const int b = m0 >> 11;                    // 256-row block never straddles batch
    const int s_base = (m0 & 2047) + wr128 + quad * 4;

    if (headg < 32) {                          // Q: plain head-major store
        half_t* outp = Qh + (size_t)(b * NH + headg) * SEQ * 64;
        #pragma unroll
        for (int m = 0; m < 8; m++)
            #pragma unroll
            for (int n = 0; n < 4; n++) {
                int d = n * 16 + l15;
                #pragma unroll
                for (int r = 0; r < 4; r++)
                    outp[(size_t)(s_base + m * 16 + r) * 64 + d] = (half_t)acc[m][n][r];
            }
    } else if (headg < 40) {                   // K: RoPE
        half_t* outp = Kh + (size_t)(b * NKV + (headg - 32)) * SEQ * 64;
        #pragma unroll
        for (int m = 0; m < 8; m++)
            #pragma unroll
            for (int r = 0; r < 4; r++) {
                int s = s_base + m * 16 + r;
                #pragma unroll
                for (int j = 0; j < 2; j++) {
                    int d = j * 16 + l15;
                    float x1 = acc[m][j][r], x2 = acc[m][j + 2][r];
                    float c1 = cosb[s * 64 + d],      s1 = sinb[s * 64 + d];
                    float c2 = cosb[s * 64 + d + 32], s2 = sinb[s * 64 + d + 32];
                    outp[(size_t)s * 64 + d]      = (half_t)(x1 * c1 - x2 * s1);
                    outp[(size_t)s * 64 + d + 32] = (half_t)(x2 * c2 + x1 * s2);
                }
            }
    } else {                                   // V: transpose to [d][s]
        half_t* vtp = Vt + (size_t)(b * NKV + (headg - 40)) * 64 * SEQ;
        #pragma unroll
        for (int m = 0; m < 8; m++) {
            int s = s_base + m * 16;
            #pragma unroll
            for (int n = 0; n < 4; n++) {
                int d = n * 16 + l15;
                half4 hv;
                hv[0] = (half_t)acc[m][n][0];
                hv[1] = (half_t)acc[m][n][1];
                hv[2] = (half_t)acc[m][n][2];
                hv[3] = (half_t)acc[m][n][3];
                *(half4*)(vtp + (size_t)d * SEQ + s) = hv;
            }
        }
    }
}

// ---------------------------------------------------------------- output projection, f32 out
__global__ __launch_bounds__(512, 2) void gemm_tn_f(
    const half_t* __restrict__ A, const half_t* __restrict__ Bt,
    float* __restrict__ C)
{
    __shared__ half_t As[2][16384];
    __shared__ half_t Bs[2][16384];
    const int m0 = blockIdx.y * 256, n0 = blockIdx.x * 256;

    floatx4 acc[8][4] = {};
    gemm256_core(A, Bt, m0, n0, &As[0][0], &Bs[0][0], acc);

    const int tid = threadIdx.x, wave = tid >> 6, lane = tid & 63;
    const int quad = lane >> 4, l15 = lane & 15;
    const int wr128 = (wave >> 2) * 128, wc64 = (wave & 3) * 64;
    #pragma unroll
    for (int m = 0; m < 8; m++) {
        int row = m0 + wr128 + m * 16 + quad * 4;
        #pragma unroll
        for (int n = 0; n < 4; n++) {
            int col = n0 + wc64 + n * 16 + l15;
            #pragma unroll
            for (int r = 0; r < 4; r++)
                C[(size_t)(row + r) * DOUT + col] = acc[m][n][r];
        }
    }
}

// ---------------------------------------------------------------- causal GQA flash attention (S^T layout) — unchanged
__global__ __launch_bounds__(256, 4) void attn(
    const half_t* __restrict__ Qh, const half_t* __restrict__ Kh,
    const half_t* __restrict__ Vt, const float* __restrict__ cosb,
    const float* __restrict__ sinb, half_t* __restrict__ ctx)
{
    __shared__ half_t Ks[2][4096];
    __shared__ half_t Vs[2][4096];

    const int tid = threadIdx.x, wave = tid >> 6, lane = tid & 63;
    const int quad = lane >> 4, l15 = lane & 15;
    const int bid = blockIdx.x;
    const int k  = bid >> 8;
    const int u  = bid & 255;
    const int q2 = u & 3;
    const int bh = u >> 2;
    const int qt = (k == 0) ? 15 - 2 * q2 : (k == 1) ? 2 * q2
                 : (k == 2) ? 14 - 2 * q2 : 2 * q2 + 1;
    const int b  = bh >> 5;
    const int h  = bh & 31;
    const int g  = h >> 2;
    const int q0 = qt * 128;
    const int wm = wave * 32;

    const half_t* kp = Kh + (size_t)(b * NKV + g) * SEQ * 64;
    const half_t* vp = Vt + (size_t)(b * NKV + g) * 64 * SEQ;

    half8 qf[2][2];
    {
        const float sc = 0.125f * 1.44269504088896f;
        const half_t* qpp = Qh + ((size_t)(b * NH + h) * SEQ + q0 + wm) * 64;
        #pragma unroll
        for (int mf = 0; mf < 2; mf++) {
            int s = q0 + wm + mf * 16 + l15;
            const float* cp = cosb + s * 64 + quad * 8;
            const float* sp = sinb + s * 64 + quad * 8;
            half8 xa = *(const half8*)(qpp + (size_t)(mf * 16 + l15) * 64 + quad * 8);
            half8 xb = *(const half8*)(qpp + (size_t)(mf * 16 + l15) * 64 + 32 + quad * 8);
            float4 c1a = *(const float4*)(cp),      c1b = *(const float4*)(cp + 4);
            float4 s1a = *(const float4*)(sp),      s1b = *(const float4*)(sp + 4);
            float4 c2a = *(const float4*)(cp + 32), c2b = *(const float4*)(cp + 36);
            float4 s2a = *(const float4*)(sp + 32), s2b = *(const float4*)(sp + 36);
            #pragma unroll
            for (int t = 0; t < 8; t++) {
                float cc1 = (t < 4) ? ((const float*)&c1a)[t] : ((const float*)&c1b)[t - 4];
                float ss1 = (t < 4) ? ((const float*)&s1a)[t] : ((const float*)&s1b)[t - 4];
                float cc2 = (t < 4) ? ((const float*)&c2a)[t] : ((const float*)&c2b)[t - 4];
                float ss2 = (t < 4) ? ((const float*)&s2a)[t] : ((const float*)&s2b)[t - 4];
                float x1 = (float)xa[t], x2 = (float)xb[t];
                qf[mf][0][t] = (half_t)((x1 * cc1 - x2 * ss1) * sc);
                qf[mf][1][t] = (half_t)((x2 * cc2 + x1 * ss2) * sc);
            }
        }
    }

    int koff[2], voff[2], lo[2];
    #pragma unroll
    for (int is = 0; is < 2; is++) {
        int s = is * 256 + tid;
        int p = s >> 3, c = (s & 7) ^ (p & 7);
        koff[is] = p * 64 + c * 8;
        voff[is] = p * SEQ + c * 8;
        lo[is]   = (is * 256 + wave * 64) * 8;
    }

    float m_i[2], l_i[2];
    m_i[0] = m_i[1] = -__builtin_inff();
    l_i[0] = l_i[1] = 0.f;
    floatx4 o[2][4] = {};

    const int ntiles = 2 * qt + 2;
    #pragma unroll
    for (int is = 0; is < 2; is++) {
        gload16(&Ks[0][lo[is]], kp + koff[is]);
        gload16(&Vs[0][lo[is]], vp + voff[is]);
    }

    const int srcA = l15 + ((quad & 1) ? 32 : 0);
    const int srcB = srcA + 16;
    const bool hiK = (quad >> 1) != 0;

    for (int kt = 0; kt < ntiles; kt++) {
        const int cur = kt & 1;
        const int kb  = kt * 64;
        __syncthreads();
        if (kt + 1 < ntiles) {
            const int kb2 = (kt + 1) * 64;
            #pragma unroll
            for (int is = 0; is < 2; is++) {
                gload16(&Ks[cur ^ 1][lo[is]], kp + (size_t)kb2 * 64 + koff[is]);
                gload16(&Vs[cur ^ 1][lo[is]], vp + kb2 + voff[is]);
            }
        }

        if (kb <= q0 + wm + 31) {
            floatx4 sa[2][4] = {};
            #pragma unroll
            for (int kc = 0; kc < 2; kc++)
                #pragma unroll
                for (int kf = 0; kf < 4; kf++) {
                    int row = kf * 16 + l15;
                    int sc = ((kc * 4 + quad) ^ (row & 7));
                    half8 kfr = *(const half8*)&Ks[cur][row * 64 + sc * 8];
                    sa[0][kf] = __builtin_amdgcn_mfma_f32_16x16x32_f16(kfr, qf[0][kc], sa[0][kf], 0, 0, 0);
                    sa[1][kf] = __builtin_amdgcn_mfma_f32_16x16x32_f16(kfr, qf[1][kc], sa[1][kf], 0, 0, 0);
                }

            if (kb + 63 > q0 + wm) {
                #pragma unroll
                for (int kf = 0; kf < 4; kf++)
                    #pragma unroll
                    for (int r = 0; r < 4; r++) {
                        int key = kb + kf * 16 + quad * 4 + r;
                        if (key > q0 + wm + l15)      sa[0][kf][r] = -__builtin_inff();
                        if (key > q0 + wm + 16 + l15) sa[1][kf][r] = -__builtin_inff();
                    }
            }

            int eh[2][4][2];
            float alpha[2];
            #pragma unroll
            for (int mf = 0; mf < 2; mf++) {
                float mt = sa[mf][0][0];
                #pragma unroll
                for (int kf = 0; kf < 4; kf++)
                    #pragma unroll
                    for (int r = 0; r < 4; r++) mt = fmaxf(mt, sa[mf][kf][r]);
                mt = fmaxf(mt, __shfl_xor(mt, 16));
                mt = fmaxf(mt, __shfl_xor(mt, 32));
                float mn = fmaxf(m_i[mf], mt);
                alpha[mf] = EXP2F(m_i[mf] - mn);
                m_i[mf] = mn;
                float rs = 0.f;
                #pragma unroll
                for (int kf = 0; kf < 4; kf++) {
                    float e0 = EXP2F(sa[mf][kf][0] - mn);
                    float e1 = EXP2F(sa[mf][kf][1] - mn);
                    float e2 = EXP2F(sa[mf][kf][2] - mn);
                    float e3 = EXP2F(sa[mf][kf][3] - mn);
                    rs += (e0 + e1) + (e2 + e3);
                    H2I p01, p23;
                    p01.h = __builtin_amdgcn_cvt_pkrtz(e0, e1);
                    p23.h = __builtin_amdgcn_cvt_pkrtz(e2, e3);
                    eh[mf][kf][0] = p01.i;
                    eh[mf][kf][1] = p23.i;
                }
                rs += __shfl_xor(rs, 16);
                rs += __shfl_xor(rs, 32);
                l_i[mf] = l_i[mf] * alpha[mf] + rs;
                #pragma unroll
                for (int nf = 0; nf < 4; nf++)
                    #pragma unroll
                    for (int r = 0; r < 4; r++) o[mf][nf][r] *= alpha[mf];
            }

            #pragma unroll
            for (int kc = 0; kc < 2; kc++) {
                H8U pf[2];
                #pragma unroll
                for (int mf = 0; mf < 2; mf++) {
                    int a0 = __shfl(eh[mf][2 * kc][0],     srcA);
                    int a1 = __shfl(eh[mf][2 * kc][1],     srcA);
                    int b0 = __shfl(eh[mf][2 * kc + 1][0], srcA);
                    int b1 = __shfl(eh[mf][2 * kc + 1][1], srcA);
                    int c0 = __shfl(eh[mf][2 * kc][0],     srcB);
                    int c1 = __shfl(eh[mf][2 * kc][1],     srcB);
                    int d0 = __shfl(eh[mf][2 * kc + 1][0], srcB);
                    int d1 = __shfl(eh[mf][2 * kc + 1][1], srcB);
                    pf[mf].u[0] = hiK ? b0 : a0;
                    pf[mf].u[1] = hiK ? b1 : a1;
                    pf[mf].u[2] = hiK ? d0 : c0;
                    pf[mf].u[3] = hiK ? d1 : c1;
                }
                #pragma unroll
                for (int nf = 0; nf < 4; nf++) {
                    int row = nf * 16 + l15;
                    int sc = ((kc * 4 + quad) ^ (row & 7));
                    half8 vf = *(const half8*)&Vs[cur][row * 64 + sc * 8];
                    o[0][nf] = __builtin_amdgcn_mfma_f32_16x16x32_f16(vf, pf[0].h, o[0][nf], 0, 0, 0);
                    o[1][nf] = __builtin_amdgcn_mfma_f32_16x16x32_f16(vf, pf[1].h, o[1][nf], 0, 0, 0);
                }
            }
        }
    }

    #pragma unroll
    for (int mf = 0; mf < 2; mf++) {
        float inv = 1.0f / l_i[mf];
        int s = q0 + wm + mf * 16 + l15;
        half_t* op = ctx + (size_t)(b * SEQ + s) * DOUT + h * 64 + quad * 4;
        #pragma unroll
        for (int nf = 0; nf < 4; nf++) {
            half4 hv;
            hv[0] = (half_t)(o[mf][nf][0] * inv);
            hv[1] = (half_t)(o[mf][nf][1] * inv);
            hv[2] = (half_t)(o[mf][nf][2] * inv);
            hv[3] = (half_t)(o[mf][nf][3] * inv);
            *(half4*)(op + nf * 16) = hv;
        }
    }
}

// ---------------------------------------------------------------- launch
extern "C" void kernel_launch(void* const* d_in, const int* in_sizes, int n_in,
                              void* d_out, int out_size, void* d_ws, size_t ws_size,
                              hipStream_t stream) {
    const float* x    = (const float*)d_in[0];
    const float* cosb = (const float*)d_in[1];
    const float* sinb = (const float*)d_in[2];
    const float* Wq   = (const float*)d_in[4];
    const float* Wk   = (const float*)d_in[5];
    const float* Wv   = (const float*)d_in[6];
    const float* Wo   = (const float*)d_in[7];
    float* out = (float*)d_out;

    const size_t M  = (size_t)BB * SEQ;   // 4096
    const size_t nX = M * DIN;

    char* ws = (char*)d_ws;
    const size_t MB = 1048576;
    half_t* xh     = (half_t*)(ws);              // 16 MiB
    half_t* WqkvT  = (half_t*)(ws + 16 * MB);    // 12 MiB  [3072][2048]
    half_t* WoT    = (half_t*)(ws + 28 * MB);    //  8 MiB
    half_t* Qh     = (half_t*)(ws + 36 * MB);    // 16 MiB  [b][h][s][64] (raw, pre-RoPE)
    half_t* Kh     = (half_t*)(ws + 52 * MB);    //  4 MiB  [b][g][s][64] (RoPE'd)
    half_t* Vt     = (half_t*)(ws + 56 * MB);    //  4 MiB  [b][g][d][SEQ]
    half_t* ctxh   = (half_t*)(ws + 60 * MB);    // 16 MiB  [b][s][h*64]

    cast_f2h<<<(nX / 4) / 256, 256, 0, stream>>>(x, xh, nX / 4);
    tcast<<<dim3(64, 64), 256, 0, stream>>>(Wq, WqkvT, DIN, DOUT);
    tcast<<<dim3(16, 64), 256, 0, stream>>>(Wk, WqkvT + (size_t)2048 * 2048, DIN, 512);
    tcast<<<dim3(16, 64), 256, 0, stream>>>(Wv, WqkvT + (size_t)2560 * 2048, DIN, 512);
    tcast<<<dim3(64, 64), 256, 0, stream>>>(Wo, WoT, DOUT, DOUT);

    // fused QKV projection + K-RoPE + relayout (12x16 = 192 blocks)
    gemm_qkv<<<dim3(3072 / 256, M / 256), 512, 0, stream>>>(xh, WqkvT, cosb, sinb, Qh, Kh, Vt);

    // attention (Q-RoPE fused at load)
    attn<<<BB * NH * (SEQ / 128), 256, 0, stream>>>(Qh, Kh, Vt, cosb, sinb, ctxh);

    // output projection (8x16 = 128 blocks)
    gemm_tn_f<<<dim3(DOUT / 256, M / 256), 512, 0, stream>>>(ctxh, WoT, out);
}

// Round 3
// 342.744 us; speedup vs baseline: 1.1173x; 1.0345x over previous
//
#include <hip/hip_runtime.h>
#include <hip/hip_fp16.h>

#define SEQ    2048
#define DIN    2048
#define DOUT   2048
#define NH     32
#define NKV    8
#define HD     64
#define BB     2

typedef _Float16 half_t;
typedef __attribute__((ext_vector_type(8))) _Float16 half8;
typedef __attribute__((ext_vector_type(4))) _Float16 half4;
typedef __attribute__((ext_vector_type(2))) __fp16   fp16x2;
typedef __attribute__((ext_vector_type(4))) float    floatx4;

union H8U { half8 h; int u[4]; };
union H2I { fp16x2 h; int i; };

#if __has_builtin(__builtin_amdgcn_exp2f)
#define EXP2F(x) __builtin_amdgcn_exp2f(x)
#else
#define EXP2F(x) __expf((x) * 0.6931471805599453f)
#endif

// async 16B global->LDS (wave-uniform LDS base + lane*16)
__device__ __forceinline__ void gload16(void* l, const void* g) {
    __builtin_amdgcn_global_load_lds(
        (const __attribute__((address_space(1))) void*)g,
        (__attribute__((address_space(3))) void*)l, 16, 0, 0);
}

// ---------------------------------------------------------------- cast f32->f16
__global__ void cast_f2h(const float* __restrict__ in, half_t* __restrict__ out, int n4) {
    int i = blockIdx.x * blockDim.x + threadIdx.x;
    if (i < n4) {
        float4 v = ((const float4*)in)[i];
        half4 h;
        h[0] = (half_t)v.x; h[1] = (half_t)v.y; h[2] = (half_t)v.z; h[3] = (half_t)v.w;
        ((half4*)out)[i] = h;
    }
}

// ---------------------------------------------------------------- transpose+cast: f32 [Kd][Nd] -> f16 [Nd][Kd]
__global__ __launch_bounds__(256) void tcast(const float* __restrict__ in, half_t* __restrict__ out,
                                             int Kd, int Nd) {
    __shared__ float T[32][33];
    int x0 = blockIdx.x * 32, y0 = blockIdx.y * 32;
    int tx = threadIdx.x & 31, ty = threadIdx.x >> 5;
    #pragma unroll
    for (int j = 0; j < 4; j++)
        T[ty + j * 8][tx] = in[(size_t)(y0 + ty + j * 8) * Nd + x0 + tx];
    __syncthreads();
    #pragma unroll
    for (int j = 0; j < 4; j++)
        out[(size_t)(x0 + ty + j * 8) * Kd + y0 + tx] = (half_t)T[tx][ty + j * 8];
}

// ================================================================ 128x128 / BK=64 / 4-wave 2-phase GEMM core
// m97 structure (proven robust: compiler-managed waits, syncthreads drain
// hidden by 3 blocks/CU co-residency), BK=64 to halve the drain count.
// LDS per operand: 2 k-subblocks of [64 pairrows][8 slots][8 halves] = 16 KB.
//   slot = ((row&1)*4 + kq) ^ (pairrow&7)  (conflict-free; measured 0).
// Staging: 4 gloads/thread/operand, pre-swizzled global src, linear LDS dest.
__device__ __forceinline__ void gemm128_core(
    const half_t* __restrict__ A, const half_t* __restrict__ Bt,
    int m0, int n0, half_t* As, half_t* Bs, floatx4 (&acc)[4][4])
{
    const int tid = threadIdx.x, wave = tid >> 6, lane = tid & 63;
    const int quad = lane >> 4, l15 = lane & 15;
    const int wm = (wave >> 1) * 64, wn = (wave & 1) * 64;
    const int K = DIN;

    const half_t* pa[4]; const half_t* pb[4]; int ldso[4];
    #pragma unroll
    for (int is = 0; is < 4; is++) {
        int s  = is * 256 + tid;        // [0,1024) 8-half groups
        int kb = s >> 9, s1 = s & 511;  // k-subblock, intra
        int p  = s1 >> 3, sc = s1 & 7;
        int c  = sc ^ (p & 7);
        int row  = 2 * p + (c >> 2);
        int koff = kb * 32 + (c & 3) * 8;
        pa[is] = A  + (size_t)(m0 + row) * K + koff;
        pb[is] = Bt + (size_t)(n0 + row) * K + koff;
        ldso[is] = (is * 256 + wave * 64) * 8;
    }
    int aoff[4], boff[4];
    #pragma unroll
    for (int m = 0; m < 4; m++) {
        int r = wm + m * 16 + l15, p = r >> 1;
        aoff[m] = p * 64 + ((((r & 1) * 4 + quad) ^ (p & 7)) * 8);
        int rn = wn + m * 16 + l15, pn = rn >> 1;
        boff[m] = pn * 64 + ((((rn & 1) * 4 + quad) ^ (pn & 7)) * 8);
    }

    for (int k0 = 0; k0 < K; k0 += 64) {
        __syncthreads();                 // all waves done reading LDS
        #pragma unroll
        for (int is = 0; is < 4; is++) {
            gload16(As + ldso[is], pa[is] + k0);
            gload16(Bs + ldso[is], pb[is] + k0);
        }
        __syncthreads();                 // staging landed (vmcnt drain, hidden by co-resident blocks)
        half8 af[4][2], bf[4][2];
        #pragma unroll
        for (int i = 0; i < 4; i++) {
            af[i][0] = *(const half8*)(As + aoff[i]);
            af[i][1] = *(const half8*)(As + 4096 + aoff[i]);
            bf[i][0] = *(const half8*)(Bs + boff[i]);
            bf[i][1] = *(const half8*)(Bs + 4096 + boff[i]);
        }
        #pragma unroll
        for (int i = 0; i < 4; i++)
            #pragma unroll
            for (int j = 0; j < 4; j++)
                #pragma unroll
                for (int ks = 0; ks < 2; ks++)
                    acc[i][j] = __builtin_amdgcn_mfma_f32_16x16x32_f16(af[i][ks], bf[j][ks], acc[i][j], 0, 0, 0);
    }
}

// ---------------------------------------------------------------- fused QKV GEMM + K-RoPE + relayout
// C = xh[4096x2048] @ WqkvT[3072x2048]^T ; each wave's 64-col span = one head:
//   cols <2048  : plain store -> Qh [b][h][s][64]
//   2048..2559  : RoPE        -> Kh [b][g][s][64]
//   2560..3071  : transpose   -> Vt [b][g][d][SEQ]
// 1D grid 768 = 32 m-tiles x 24 n-tiles, XCD-chunked swizzle (T1, bijective:
// 768%8==0): XCD x owns wg [96x,96x+96) = 3 n-panels (1.5 MB B hot in its L2).
__global__ __launch_bounds__(256) void gemm_qkv(
    const half_t* __restrict__ A, const half_t* __restrict__ Bt,
    const float* __restrict__ cosb, const float* __restrict__ sinb,
    half_t* __restrict__ Qh, half_t* __restrict__ Kh, half_t* __restrict__ Vt)
{
    __shared__ half_t As[8192];
    __shared__ half_t Bs[8192];
    const int bid = blockIdx.x;
    const int wg  = (bid & 7) * 96 + (bid >> 3);   // XCD-chunked remap
    const int m0  = (wg & 31) * 128;               // m fastest within chunk
    const int n0  = (wg >> 5) * 128;

    floatx4 acc[4][4] = {};
    gemm128_core(A, Bt, m0, n0, As, Bs, acc);

    const int tid = threadIdx.x, wave = tid >> 6, lane = tid & 63;
    const int quad = lane >> 4, l15 = lane & 15;
    const int wm = (wave >> 1) * 64, wn = (wave & 1) * 64;
    const int headg = (n0 + wn) >> 6;          // 0..47
    const int b = m0 >> 11;                    // block never straddles batch
    const int s_base = (m0 & 2047) + wm + quad * 4;

    if (headg < 32) {                          // Q: plain head-major store
        half_t* outp = Qh + (size_t)(b * NH + headg) * SEQ * 64;
        #pragma unroll
        for (int i = 0; i < 4; i++)
            #pragma unroll
            for (int j = 0; j < 4; j++) {
                int d = j * 16 + l15;
                #pragma unroll
                for (int r = 0; r < 4; r++)
                    outp[(size_t)(s_base + i * 16 + r) * 64 + d] = (half_t)acc[i][j][r];
            }
    } else if (headg < 40) {                   // K: RoPE
        half_t* outp = Kh + (size_t)(b * NKV + (headg - 32)) * SEQ * 64;
        #pragma unroll
        for (int i = 0; i < 4; i++)
            #pragma unroll
            for (int r = 0; r < 4; r++) {
                int s = s_base + i * 16 + r;
                #pragma unroll
                for (int j = 0; j < 2; j++) {
                    int d = j * 16 + l15;
                    float x1 = acc[i][j][r], x2 = acc[i][j + 2][r];
                    float c1 = cosb[s * 64 + d],      s1 = sinb[s * 64 + d];
                    float c2 = cosb[s * 64 + d + 32], s2 = sinb[s * 64 + d + 32];
                    outp[(size_t)s * 64 + d]      = (half_t)(x1 * c1 - x2 * s1);
                    outp[(size_t)s * 64 + d + 32] = (half_t)(x2 * c2 + x1 * s2);
                }
            }
    } else {                                   // V: transpose to [d][s]
        half_t* vtp = Vt + (size_t)(b * NKV + (headg - 40)) * 64 * SEQ;
        #pragma unroll
        for (int i = 0; i < 4; i++) {
            int s = s_base + i * 16;
            #pragma unroll
            for (int j = 0; j < 4; j++) {
                int d = j * 16 + l15;
                half4 hv;
                hv[0] = (half_t)acc[i][j][0];
                hv[1] = (half_t)acc[i][j][1];
                hv[2] = (half_t)acc[i][j][2];
                hv[3] = (half_t)acc[i][j][3];
                *(half4*)(vtp + (size_t)d * SEQ + s) = hv;
            }
        }
    }
}

// ---------------------------------------------------------------- output projection, f32 out
// 1D grid 512 = 32 m x 16 n, XCD-chunked swizzle (512%8==0): 2 n-panels/XCD hot.
__global__ __launch_bounds__(256) void gemm_tn_f(
    const half_t* __restrict__ A, const half_t* __restrict__ Bt,
    float* __restrict__ C)
{
    __shared__ half_t As[8192];
    __shared__ half_t Bs[8192];
    const int bid = blockIdx.x;
    const int wg  = (bid & 7) * 64 + (bid >> 3);
    const int m0  = (wg & 31) * 128;
    const int n0  = (wg >> 5) * 128;

    floatx4 acc[4][4] = {};
    gemm128_core(A, Bt, m0, n0, As, Bs, acc);

    const int tid = threadIdx.x, wave = tid >> 6, lane = tid & 63;
    const int quad = lane >> 4, l15 = lane & 15;
    const int wm = (wave >> 1) * 64, wn = (wave & 1) * 64;
    #pragma unroll
    for (int i = 0; i < 4; i++) {
        int row = m0 + wm + i * 16 + quad * 4;
        #pragma unroll
        for (int j = 0; j < 4; j++) {
            int col = n0 + wn + j * 16 + l15;
            #pragma unroll
            for (int r = 0; r < 4; r++)
                C[(size_t)(row + r) * DOUT + col] = acc[i][j][r];
        }
    }
}

// ---------------------------------------------------------------- causal GQA flash attention (S^T layout) — unchanged
__global__ __launch_bounds__(256, 4) void attn(
    const half_t* __restrict__ Qh, const half_t* __restrict__ Kh,
    const half_t* __restrict__ Vt, const float* __restrict__ cosb,
    const float* __restrict__ sinb, half_t* __restrict__ ctx)
{
    __shared__ half_t Ks[2][4096];
    __shared__ half_t Vs[2][4096];

    const int tid = threadIdx.x, wave = tid >> 6, lane = tid & 63;
    const int quad = lane >> 4, l15 = lane & 15;
    const int bid = blockIdx.x;
    const int k  = bid >> 8;
    const int u  = bid & 255;
    const int q2 = u & 3;
    const int bh = u >> 2;
    const int qt = (k == 0) ? 15 - 2 * q2 : (k == 1) ? 2 * q2
                 : (k == 2) ? 14 - 2 * q2 : 2 * q2 + 1;
    const int b  = bh >> 5;
    const int h  = bh & 31;
    const int g  = h >> 2;
    const int q0 = qt * 128;
    const int wm = wave * 32;

    const half_t* kp = Kh + (size_t)(b * NKV + g) * SEQ * 64;
    const half_t* vp = Vt + (size_t)(b * NKV + g) * 64 * SEQ;

    half8 qf[2][2];
    {
        const float sc = 0.125f * 1.44269504088896f;
        const half_t* qpp = Qh + ((size_t)(b * NH + h) * SEQ + q0 + wm) * 64;
        #pragma unroll
        for (int mf = 0; mf < 2; mf++) {
            int s = q0 + wm + mf * 16 + l15;
            const float* cp = cosb + s * 64 + quad * 8;
            const float* sp = sinb + s * 64 + quad * 8;
            half8 xa = *(const half8*)(qpp + (size_t)(mf * 16 + l15) * 64 + quad * 8);
            half8 xb = *(const half8*)(qpp + (size_t)(mf * 16 + l15) * 64 + 32 + quad * 8);
            float4 c1a = *(const float4*)(cp),      c1b = *(const float4*)(cp + 4);
            float4 s1a = *(const float4*)(sp),      s1b = *(const float4*)(sp + 4);
            float4 c2a = *(const float4*)(cp + 32), c2b = *(const float4*)(cp + 36);
            float4 s2a = *(const float4*)(sp + 32), s2b = *(const float4*)(sp + 36);
            #pragma unroll
            for (int t = 0; t < 8; t++) {
                float cc1 = (t < 4) ? ((const float*)&c1a)[t] : ((const float*)&c1b)[t - 4];
                float ss1 = (t < 4) ? ((const float*)&s1a)[t] : ((const float*)&s1b)[t - 4];
                float cc2 = (t < 4) ? ((const float*)&c2a)[t] : ((const float*)&c2b)[t - 4];
                float ss2 = (t < 4) ? ((const float*)&s2a)[t] : ((const float*)&s2b)[t - 4];
                float x1 = (float)xa[t], x2 = (float)xb[t];
                qf[mf][0][t] = (half_t)((x1 * cc1 - x2 * ss1) * sc);
                qf[mf][1][t] = (half_t)((x2 * cc2 + x1 * ss2) * sc);
            }
        }
    }

    int koff[2], voff[2], lo[2];
    #pragma unroll
    for (int is = 0; is < 2; is++) {
        int s = is * 256 + tid;
        int p = s >> 3, c = (s & 7) ^ (p & 7);
        koff[is] = p * 64 + c * 8;
        voff[is] = p * SEQ + c * 8;
        lo[is]   = (is * 256 + wave * 64) * 8;
    }

    float m_i[2], l_i[2];
    m_i[0] = m_i[1] = -__builtin_inff();
    l_i[0] = l_i[1] = 0.f;
    floatx4 o[2][4] = {};

    const int ntiles = 2 * qt + 2;
    #pragma unroll
    for (int is = 0; is < 2; is++) {
        gload16(&Ks[0][lo[is]], kp + koff[is]);
        gload16(&Vs[0][lo[is]], vp + voff[is]);
    }

    const int srcA = l15 + ((quad & 1) ? 32 : 0);
    const int srcB = srcA + 16;
    const bool hiK = (quad >> 1) != 0;

    for (int kt = 0; kt < ntiles; kt++) {
        const int cur = kt & 1;
        const int kb  = kt * 64;
        __syncthreads();
        if (kt + 1 < ntiles) {
            const int kb2 = (kt + 1) * 64;
            #pragma unroll
            for (int is = 0; is < 2; is++) {
                gload16(&Ks[cur ^ 1][lo[is]], kp + (size_t)kb2 * 64 + koff[is]);
                gload16(&Vs[cur ^ 1][lo[is]], vp + kb2 + voff[is]);
            }
        }

        if (kb <= q0 + wm + 31) {
            floatx4 sa[2][4] = {};
            #pragma unroll
            for (int kc = 0; kc < 2; kc++)
                #pragma unroll
                for (int kf = 0; kf < 4; kf++) {
                    int row = kf * 16 + l15;
                    int sc = ((kc * 4 + quad) ^ (row & 7));
                    half8 kfr = *(const half8*)&Ks[cur][row * 64 + sc * 8];
                    sa[0][kf] = __builtin_amdgcn_mfma_f32_16x16x32_f16(kfr, qf[0][kc], sa[0][kf], 0, 0, 0);
                    sa[1][kf] = __builtin_amdgcn_mfma_f32_16x16x32_f16(kfr, qf[1][kc], sa[1][kf], 0, 0, 0);
                }

            if (kb + 63 > q0 + wm) {
                #pragma unroll
                for (int kf = 0; kf < 4; kf++)
                    #pragma unroll
                    for (int r = 0; r < 4; r++) {
                        int key = kb + kf * 16 + quad * 4 + r;
                        if (key > q0 + wm + l15)      sa[0][kf][r] = -__builtin_inff();
                        if (key > q0 + wm + 16 + l15) sa[1][kf][r] = -__builtin_inff();
                    }
            }

            int eh[2][4][2];
            float alpha[2];
            #pragma unroll
            for (int mf = 0; mf < 2; mf++) {
                float mt = sa[mf][0][0];
                #pragma unroll
                for (int kf = 0; kf < 4; kf++)
                    #pragma unroll
                    for (int r = 0; r < 4; r++) mt = fmaxf(mt, sa[mf][kf][r]);
                mt = fmaxf(mt, __shfl_xor(mt, 16));
                mt = fmaxf(mt, __shfl_xor(mt, 32));
                float mn = fmaxf(m_i[mf], mt);
                alpha[mf] = EXP2F(m_i[mf] - mn);
                m_i[mf] = mn;
                float rs = 0.f;
                #pragma unroll
                for (int kf = 0; kf < 4; kf++) {
                    float e0 = EXP2F(sa[mf][kf][0] - mn);
                    float e1 = EXP2F(sa[mf][kf][1] - mn);
                    float e2 = EXP2F(sa[mf][kf][2] - mn);
                    float e3 = EXP2F(sa[mf][kf][3] - mn);
                    rs += (e0 + e1) + (e2 + e3);
                    H2I p01, p23;
                    p01.h = __builtin_amdgcn_cvt_pkrtz(e0, e1);
                    p23.h = __builtin_amdgcn_cvt_pkrtz(e2, e3);
                    eh[mf][kf][0] = p01.i;
                    eh[mf][kf][1] = p23.i;
                }
                rs += __shfl_xor(rs, 16);
                rs += __shfl_xor(rs, 32);
                l_i[mf] = l_i[mf] * alpha[mf] + rs;
                #pragma unroll
                for (int nf = 0; nf < 4; nf++)
                    #pragma unroll
                    for (int r = 0; r < 4; r++) o[mf][nf][r] *= alpha[mf];
            }

            #pragma unroll
            for (int kc = 0; kc < 2; kc++) {
                H8U pf[2];
                #pragma unroll
                for (int mf = 0; mf < 2; mf++) {
                    int a0 = __shfl(eh[mf][2 * kc][0],     srcA);
                    int a1 = __shfl(eh[mf][2 * kc][1],     srcA);
                    int b0 = __shfl(eh[mf][2 * kc + 1][0], srcA);
                    int b1 = __shfl(eh[mf][2 * kc + 1][1], srcA);
                    int c0 = __shfl(eh[mf][2 * kc][0],     srcB);
                    int c1 = __shfl(eh[mf][2 * kc][1],     srcB);
                    int d0 = __shfl(eh[mf][2 * kc + 1][0], srcB);
                    int d1 = __shfl(eh[mf][2 * kc + 1][1], srcB);
                    pf[mf].u[0] = hiK ? b0 : a0;
                    pf[mf].u[1] = hiK ? b1 : a1;
                    pf[mf].u[2] = hiK ? d0 : c0;
                    pf[mf].u[3] = hiK ? d1 : c1;
                }
                #pragma unroll
                for (int nf = 0; nf < 4; nf++) {
                    int row = nf * 16 + l15;
                    int sc = ((kc * 4 + quad) ^ (row & 7));
                    half8 vf = *(const half8*)&Vs[cur][row * 64 + sc * 8];
                    o[0][nf] = __builtin_amdgcn_mfma_f32_16x16x32_f16(vf, pf[0].h, o[0][nf], 0, 0, 0);
                    o[1][nf] = __builtin_amdgcn_mfma_f32_16x16x32_f16(vf, pf[1].h, o[1][nf], 0, 0, 0);
                }
            }
        }
    }

    #pragma unroll
    for (int mf = 0; mf < 2; mf++) {
        float inv = 1.0f / l_i[mf];
        int s = q0 + wm + mf * 16 + l15;
        half_t* op = ctx + (size_t)(b * SEQ + s) * DOUT + h * 64 + quad * 4;
        #pragma unroll
        for (int nf = 0; nf < 4; nf++) {
            half4 hv;
            hv[0] = (half_t)(o[mf][nf][0] * inv);
            hv[1] = (half_t)(o[mf][nf][1] * inv);
            hv[2] = (half_t)(o[mf][nf][2] * inv);
            hv[3] = (half_t)(o[mf][nf][3] * inv);
            *(half4*)(op + nf * 16) = hv;
        }
    }
}

// ---------------------------------------------------------------- launch
extern "C" void kernel_launch(void* const* d_in, const int* in_sizes, int n_in,
                              void* d_out, int out_size, void* d_ws, size_t ws_size,
                              hipStream_t stream) {
    const float* x    = (const float*)d_in[0];
    const float* cosb = (const float*)d_in[1];
    const float* sinb = (const float*)d_in[2];
    const float* Wq   = (const float*)d_in[4];
    const float* Wk   = (const float*)d_in[5];
    const float* Wv   = (const float*)d_in[6];
    const float* Wo   = (const float*)d_in[7];
    float* out = (float*)d_out;

    const size_t M  = (size_t)BB * SEQ;   // 4096
    const size_t nX = M * DIN;

    char* ws = (char*)d_ws;
    const size_t MB = 1048576;
    half_t* xh     = (half_t*)(ws);              // 16 MiB
    half_t* WqkvT  = (half_t*)(ws + 16 * MB);    // 12 MiB  [3072][2048]
    half_t* WoT    = (half_t*)(ws + 28 * MB);    //  8 MiB
    half_t* Qh     = (half_t*)(ws + 36 * MB);    // 16 MiB  [b][h][s][64] (raw, pre-RoPE)
    half_t* Kh     = (half_t*)(ws + 52 * MB);    //  4 MiB  [b][g][s][64] (RoPE'd)
    half_t* Vt     = (half_t*)(ws + 56 * MB);    //  4 MiB  [b][g][d][SEQ]
    half_t* ctxh   = (half_t*)(ws + 60 * MB);    // 16 MiB  [b][s][h*64]

    cast_f2h<<<(nX / 4) / 256, 256, 0, stream>>>(x, xh, nX / 4);
    tcast<<<dim3(64, 64), 256, 0, stream>>>(Wq, WqkvT, DIN, DOUT);
    tcast<<<dim3(16, 64), 256, 0, stream>>>(Wk, WqkvT + (size_t)2048 * 2048, DIN, 512);
    tcast<<<dim3(16, 64), 256, 0, stream>>>(Wv, WqkvT + (size_t)2560 * 2048, DIN, 512);
    tcast<<<dim3(64, 64), 256, 0, stream>>>(Wo, WoT, DOUT, DOUT);

    // fused QKV projection + K-RoPE + relayout (768 blocks, XCD-swizzled)
    gemm_qkv<<<768, 256, 0, stream>>>(xh, WqkvT, cosb, sinb, Qh, Kh, Vt);

    // attention (Q-RoPE fused at load)
    attn<<<BB * NH * (SEQ / 128), 256, 0, stream>>>(Qh, Kh, Vt, cosb, sinb, ctxh);

    // output projection (512 blocks, XCD-swizzled)
    gemm_tn_f<<<512, 256, 0, stream>>>(ctxh, WoT, out);
}

// Round 4
// 315.428 us; speedup vs baseline: 1.2141x; 1.0866x over previous
//
#include <hip/hip_runtime.h>
#include <hip/hip_fp16.h>

#define SEQ    2048
#define DIN    2048
#define DOUT   2048
#define NH     32
#define NKV    8
#define HD     64
#define BB     2

typedef _Float16 half_t;
typedef __attribute__((ext_vector_type(8))) _Float16 half8;
typedef __attribute__((ext_vector_type(4))) _Float16 half4;
typedef __attribute__((ext_vector_type(2))) __fp16   fp16x2;
typedef __attribute__((ext_vector_type(4))) float    floatx4;

union H8U { half8 h; int u[4]; };
union H2I { fp16x2 h; int i; };

#if __has_builtin(__builtin_amdgcn_exp2f)
#define EXP2F(x) __builtin_amdgcn_exp2f(x)
#else
#define EXP2F(x) __expf((x) * 0.6931471805599453f)
#endif

// async 16B global->LDS (wave-uniform LDS base + lane*16)
__device__ __forceinline__ void gload16(void* l, const void* g) {
    __builtin_amdgcn_global_load_lds(
        (const __attribute__((address_space(1))) void*)g,
        (__attribute__((address_space(3))) void*)l, 16, 0, 0);
}

// ---------------------------------------------------------------- fused prep:
// one dispatch = cast x f32->f16 (blocks 0..8191) + 4 transpose-casts
// (Wq|Wk|Wv -> WqkvT [3072][2048], Wo -> WoT [2048][2048]).
__global__ __launch_bounds__(256) void prep(
    const float* __restrict__ x,
    const float* __restrict__ Wq, const float* __restrict__ Wk,
    const float* __restrict__ Wv, const float* __restrict__ Wo,
    half_t* __restrict__ xh, half_t* __restrict__ WqkvT, half_t* __restrict__ WoT)
{
    __shared__ float T[32][33];
    int bid = blockIdx.x;
    if (bid < 8192) {                       // cast x (4096*2048 f32, float4/thread)
        int i = bid * 256 + threadIdx.x;
        float4 v = ((const float4*)x)[i];
        half4 h;
        h[0] = (half_t)v.x; h[1] = (half_t)v.y; h[2] = (half_t)v.z; h[3] = (half_t)v.w;
        ((half4*)xh)[i] = h;
        return;
    }
    bid -= 8192;
    const float* in; half_t* out; int Nd, bx, by;
    if (bid < 4096)      {            in = Wq; out = WqkvT;                        Nd = 2048; bx = bid & 63; by = bid >> 6; }
    else if (bid < 5120) { bid -= 4096; in = Wk; out = WqkvT + (size_t)2048 * 2048; Nd = 512;  bx = bid & 15; by = bid >> 4; }
    else if (bid < 6144) { bid -= 5120; in = Wv; out = WqkvT + (size_t)2560 * 2048; Nd = 512;  bx = bid & 15; by = bid >> 4; }
    else                 { bid -= 6144; in = Wo; out = WoT;                         Nd = 2048; bx = bid & 63; by = bid >> 6; }
    const int Kd = 2048;
    int x0 = bx * 32, y0 = by * 32;
    int tx = threadIdx.x & 31, ty = threadIdx.x >> 5;
    #pragma unroll
    for (int j = 0; j < 4; j++)
        T[ty + j * 8][tx] = in[(size_t)(y0 + ty + j * 8) * Nd + x0 + tx];
    __syncthreads();
    #pragma unroll
    for (int j = 0; j < 4; j++)
        out[(size_t)(x0 + ty + j * 8) * Kd + y0 + tx] = (half_t)T[tx][ty + j * 8];
}

// ================================================================ 128x128 / BK=64 / 4-wave 2-phase GEMM core
// m97 structure (compiler-managed waits; drain hidden by 3 blocks/CU),
// BK=64 halves the drain count vs BK=32 (R3: 94.4 -> 86.6 us measured).
// LDS per operand: 2 k-subblocks of [64 pairrows][8 slots][8 halves] = 16 KB.
//   slot = ((row&1)*4 + kq) ^ (pairrow&7)  (conflict-free; measured 0).
__device__ __forceinline__ void gemm128_core(
    const half_t* __restrict__ A, const half_t* __restrict__ Bt,
    int m0, int n0, half_t* As, half_t* Bs, floatx4 (&acc)[4][4])
{
    const int tid = threadIdx.x, wave = tid >> 6, lane = tid & 63;
    const int quad = lane >> 4, l15 = lane & 15;
    const int wm = (wave >> 1) * 64, wn = (wave & 1) * 64;
    const int K = DIN;

    const half_t* pa[4]; const half_t* pb[4]; int ldso[4];
    #pragma unroll
    for (int is = 0; is < 4; is++) {
        int s  = is * 256 + tid;        // [0,1024) 8-half groups
        int kb = s >> 9, s1 = s & 511;  // k-subblock, intra
        int p  = s1 >> 3, sc = s1 & 7;
        int c  = sc ^ (p & 7);
        int row  = 2 * p + (c >> 2);
        int koff = kb * 32 + (c & 3) * 8;
        pa[is] = A  + (size_t)(m0 + row) * K + koff;
        pb[is] = Bt + (size_t)(n0 + row) * K + koff;
        ldso[is] = (is * 256 + wave * 64) * 8;
    }
    int aoff[4], boff[4];
    #pragma unroll
    for (int m = 0; m < 4; m++) {
        int r = wm + m * 16 + l15, p = r >> 1;
        aoff[m] = p * 64 + ((((r & 1) * 4 + quad) ^ (p & 7)) * 8);
        int rn = wn + m * 16 + l15, pn = rn >> 1;
        boff[m] = pn * 64 + ((((rn & 1) * 4 + quad) ^ (pn & 7)) * 8);
    }

    for (int k0 = 0; k0 < K; k0 += 64) {
        __syncthreads();                 // all waves done reading LDS
        #pragma unroll
        for (int is = 0; is < 4; is++) {
            gload16(As + ldso[is], pa[is] + k0);
            gload16(Bs + ldso[is], pb[is] + k0);
        }
        __syncthreads();                 // staging landed
        half8 af[4][2], bf[4][2];
        #pragma unroll
        for (int i = 0; i < 4; i++) {
            af[i][0] = *(const half8*)(As + aoff[i]);
            af[i][1] = *(const half8*)(As + 4096 + aoff[i]);
            bf[i][0] = *(const half8*)(Bs + boff[i]);
            bf[i][1] = *(const half8*)(Bs + 4096 + boff[i]);
        }
        #pragma unroll
        for (int i = 0; i < 4; i++)
            #pragma unroll
            for (int j = 0; j < 4; j++)
                #pragma unroll
                for (int ks = 0; ks < 2; ks++)
                    acc[i][j] = __builtin_amdgcn_mfma_f32_16x16x32_f16(af[i][ks], bf[j][ks], acc[i][j], 0, 0, 0);
    }
}

// ---------------------------------------------------------------- fused QKV GEMM + Q/K-RoPE + relayout
// C = xh[4096x2048] @ WqkvT[3072x2048]^T ; each wave's 64-col span = one head:
//   cols <2048  : RoPE + scale(0.125*log2e) -> Qh [b][h][s][64]  (attn-ready)
//   2048..2559  : RoPE                      -> Kh [b][g][s][64]
//   2560..3071  : transpose                 -> Vt [b][g][d][SEQ]
// Plain 2D grid (R0 mapping, FETCH 83 MB measured vs 138 MB XCD-chunked).
__global__ __launch_bounds__(256) void gemm_qkv(
    const half_t* __restrict__ A, const half_t* __restrict__ Bt,
    const float* __restrict__ cosb, const float* __restrict__ sinb,
    half_t* __restrict__ Qh, half_t* __restrict__ Kh, half_t* __restrict__ Vt)
{
    __shared__ half_t As[8192];
    __shared__ half_t Bs[8192];
    const int m0 = blockIdx.y * 128, n0 = blockIdx.x * 128;

    floatx4 acc[4][4] = {};
    gemm128_core(A, Bt, m0, n0, As, Bs, acc);

    const int tid = threadIdx.x, wave = tid >> 6, lane = tid & 63;
    const int quad = lane >> 4, l15 = lane & 15;
    const int wm = (wave >> 1) * 64, wn = (wave & 1) * 64;
    const int headg = (n0 + wn) >> 6;          // 0..47
    const int b = m0 >> 11;                    // block never straddles batch
    const int s_base = (m0 & 2047) + wm + quad * 4;

    if (headg < 32) {                          // Q: RoPE + softmax scale (log2-domain)
        const float sc = 0.125f * 1.44269504088896f;
        half_t* outp = Qh + (size_t)(b * NH + headg) * SEQ * 64;
        #pragma unroll
        for (int i = 0; i < 4; i++)
            #pragma unroll
            for (int r = 0; r < 4; r++) {
                int s = s_base + i * 16 + r;
                #pragma unroll
                for (int j = 0; j < 2; j++) {
                    int d = j * 16 + l15;
                    float x1 = acc[i][j][r], x2 = acc[i][j + 2][r];
                    float c1 = cosb[s * 64 + d],      s1 = sinb[s * 64 + d];
                    float c2 = cosb[s * 64 + d + 32], s2 = sinb[s * 64 + d + 32];
                    outp[(size_t)s * 64 + d]      = (half_t)((x1 * c1 - x2 * s1) * sc);
                    outp[(size_t)s * 64 + d + 32] = (half_t)((x2 * c2 + x1 * s2) * sc);
                }
            }
    } else if (headg < 40) {                   // K: RoPE
        half_t* outp = Kh + (size_t)(b * NKV + (headg - 32)) * SEQ * 64;
        #pragma unroll
        for (int i = 0; i < 4; i++)
            #pragma unroll
            for (int r = 0; r < 4; r++) {
                int s = s_base + i * 16 + r;
                #pragma unroll
                for (int j = 0; j < 2; j++) {
                    int d = j * 16 + l15;
                    float x1 = acc[i][j][r], x2 = acc[i][j + 2][r];
                    float c1 = cosb[s * 64 + d],      s1 = sinb[s * 64 + d];
                    float c2 = cosb[s * 64 + d + 32], s2 = sinb[s * 64 + d + 32];
                    outp[(size_t)s * 64 + d]      = (half_t)(x1 * c1 - x2 * s1);
                    outp[(size_t)s * 64 + d + 32] = (half_t)(x2 * c2 + x1 * s2);
                }
            }
    } else {                                   // V: transpose to [d][s]
        half_t* vtp = Vt + (size_t)(b * NKV + (headg - 40)) * 64 * SEQ;
        #pragma unroll
        for (int i = 0; i < 4; i++) {
            int s = s_base + i * 16;
            #pragma unroll
            for (int j = 0; j < 4; j++) {
                int d = j * 16 + l15;
                half4 hv;
                hv[0] = (half_t)acc[i][j][0];
                hv[1] = (half_t)acc[i][j][1];
                hv[2] = (half_t)acc[i][j][2];
                hv[3] = (half_t)acc[i][j][3];
                *(half4*)(vtp + (size_t)d * SEQ + s) = hv;
            }
        }
    }
}

// ---------------------------------------------------------------- output projection, f32 out (plain 2D grid)
__global__ __launch_bounds__(256) void gemm_tn_f(
    const half_t* __restrict__ A, const half_t* __restrict__ Bt,
    float* __restrict__ C)
{
    __shared__ half_t As[8192];
    __shared__ half_t Bs[8192];
    const int m0 = blockIdx.y * 128, n0 = blockIdx.x * 128;

    floatx4 acc[4][4] = {};
    gemm128_core(A, Bt, m0, n0, As, Bs, acc);

    const int tid = threadIdx.x, wave = tid >> 6, lane = tid & 63;
    const int quad = lane >> 4, l15 = lane & 15;
    const int wm = (wave >> 1) * 64, wn = (wave & 1) * 64;
    #pragma unroll
    for (int i = 0; i < 4; i++) {
        int row = m0 + wm + i * 16 + quad * 4;
        #pragma unroll
        for (int j = 0; j < 4; j++) {
            int col = n0 + wn + j * 16 + l15;
            #pragma unroll
            for (int r = 0; r < 4; r++)
                C[(size_t)(row + r) * DOUT + col] = acc[i][j][r];
        }
    }
}

// ---------------------------------------------------------------- causal GQA flash attention (S^T layout)
// Q comes in RoPE'd + scaled (log2 domain) -> direct half8 fragment loads.
// Adds: T13 defer-max (skip O-rescale when tile max within 8 of running max),
//       T5 setprio(1) around QK^T and PV MFMA clusters (m191: attn +4-7%).
__global__ __launch_bounds__(256, 4) void attn(
    const half_t* __restrict__ Qh, const half_t* __restrict__ Kh,
    const half_t* __restrict__ Vt, half_t* __restrict__ ctx)
{
    __shared__ half_t Ks[2][4096];
    __shared__ half_t Vs[2][4096];

    const int tid = threadIdx.x, wave = tid >> 6, lane = tid & 63;
    const int quad = lane >> 4, l15 = lane & 15;
    const int bid = blockIdx.x;
    const int k  = bid >> 8;
    const int u  = bid & 255;
    const int q2 = u & 3;
    const int bh = u >> 2;
    const int qt = (k == 0) ? 15 - 2 * q2 : (k == 1) ? 2 * q2
                 : (k == 2) ? 14 - 2 * q2 : 2 * q2 + 1;
    const int b  = bh >> 5;
    const int h  = bh & 31;
    const int g  = h >> 2;
    const int q0 = qt * 128;
    const int wm = wave * 32;

    const half_t* kp = Kh + (size_t)(b * NKV + g) * SEQ * 64;
    const half_t* vp = Vt + (size_t)(b * NKV + g) * 64 * SEQ;

    // Q fragments: direct loads (RoPE + scale already applied by gemm_qkv)
    half8 qf[2][2];
    {
        const half_t* qpp = Qh + ((size_t)(b * NH + h) * SEQ + q0 + wm) * 64;
        #pragma unroll
        for (int mf = 0; mf < 2; mf++) {
            qf[mf][0] = *(const half8*)(qpp + (size_t)(mf * 16 + l15) * 64 + quad * 8);
            qf[mf][1] = *(const half8*)(qpp + (size_t)(mf * 16 + l15) * 64 + 32 + quad * 8);
        }
    }

    int koff[2], voff[2], lo[2];
    #pragma unroll
    for (int is = 0; is < 2; is++) {
        int s = is * 256 + tid;
        int p = s >> 3, c = (s & 7) ^ (p & 7);
        koff[is] = p * 64 + c * 8;
        voff[is] = p * SEQ + c * 8;
        lo[is]   = (is * 256 + wave * 64) * 8;
    }

    float m_i[2], l_i[2];
    m_i[0] = m_i[1] = -__builtin_inff();
    l_i[0] = l_i[1] = 0.f;
    floatx4 o[2][4] = {};

    const int ntiles = 2 * qt + 2;
    #pragma unroll
    for (int is = 0; is < 2; is++) {
        gload16(&Ks[0][lo[is]], kp + koff[is]);
        gload16(&Vs[0][lo[is]], vp + voff[is]);
    }

    const int srcA = l15 + ((quad & 1) ? 32 : 0);
    const int srcB = srcA + 16;
    const bool hiK = (quad >> 1) != 0;

    for (int kt = 0; kt < ntiles; kt++) {
        const int cur = kt & 1;
        const int kb  = kt * 64;
        __syncthreads();
        if (kt + 1 < ntiles) {
            const int kb2 = (kt + 1) * 64;
            #pragma unroll
            for (int is = 0; is < 2; is++) {
                gload16(&Ks[cur ^ 1][lo[is]], kp + (size_t)kb2 * 64 + koff[is]);
                gload16(&Vs[cur ^ 1][lo[is]], vp + kb2 + voff[is]);
            }
        }

        if (kb <= q0 + wm + 31) {
            // S^T = K @ Q^T : rows = keys, cols = queries
            floatx4 sa[2][4] = {};
            __builtin_amdgcn_s_setprio(1);
            #pragma unroll
            for (int kc = 0; kc < 2; kc++)
                #pragma unroll
                for (int kf = 0; kf < 4; kf++) {
                    int row = kf * 16 + l15;
                    int sc = ((kc * 4 + quad) ^ (row & 7));
                    half8 kfr = *(const half8*)&Ks[cur][row * 64 + sc * 8];
                    sa[0][kf] = __builtin_amdgcn_mfma_f32_16x16x32_f16(kfr, qf[0][kc], sa[0][kf], 0, 0, 0);
                    sa[1][kf] = __builtin_amdgcn_mfma_f32_16x16x32_f16(kfr, qf[1][kc], sa[1][kf], 0, 0, 0);
                }
            __builtin_amdgcn_s_setprio(0);

            if (kb + 63 > q0 + wm) {   // diagonal tile: mask key > query
                #pragma unroll
                for (int kf = 0; kf < 4; kf++)
                    #pragma unroll
                    for (int r = 0; r < 4; r++) {
                        int key = kb + kf * 16 + quad * 4 + r;
                        if (key > q0 + wm + l15)      sa[0][kf][r] = -__builtin_inff();
                        if (key > q0 + wm + 16 + l15) sa[1][kf][r] = -__builtin_inff();
                    }
            }

            int eh[2][4][2];   // packed half2 exp values
            #pragma unroll
            for (int mf = 0; mf < 2; mf++) {
                float mt = sa[mf][0][0];
                #pragma unroll
                for (int kf = 0; kf < 4; kf++)
                    #pragma unroll
                    for (int r = 0; r < 4; r++) mt = fmaxf(mt, sa[mf][kf][r]);
                mt = fmaxf(mt, __shfl_xor(mt, 16));
                mt = fmaxf(mt, __shfl_xor(mt, 32));
                // T13 defer-max: only rescale when the tile max grew past THR=8
                if (!__all(mt - m_i[mf] <= 8.0f)) {
                    float mn2 = fmaxf(m_i[mf], mt);
                    float a = EXP2F(m_i[mf] - mn2);
                    m_i[mf] = mn2;
                    l_i[mf] *= a;
                    #pragma unroll
                    for (int nf = 0; nf < 4; nf++)
                        #pragma unroll
                        for (int r = 0; r < 4; r++) o[mf][nf][r] *= a;
                }
                const float mn = m_i[mf];
                float rs = 0.f;
                #pragma unroll
                for (int kf = 0; kf < 4; kf++) {
                    float e0 = EXP2F(sa[mf][kf][0] - mn);
                    float e1 = EXP2F(sa[mf][kf][1] - mn);
                    float e2 = EXP2F(sa[mf][kf][2] - mn);
                    float e3 = EXP2F(sa[mf][kf][3] - mn);
                    rs += (e0 + e1) + (e2 + e3);
                    H2I p01, p23;
                    p01.h = __builtin_amdgcn_cvt_pkrtz(e0, e1);
                    p23.h = __builtin_amdgcn_cvt_pkrtz(e2, e3);
                    eh[mf][kf][0] = p01.i;
                    eh[mf][kf][1] = p23.i;
                }
                rs += __shfl_xor(rs, 16);
                rs += __shfl_xor(rs, 32);
                l_i[mf] += rs;
            }

            // O^T += V^T @ P^T  (P^T B-frag via in-register shuffles)
            #pragma unroll
            for (int kc = 0; kc < 2; kc++) {
                H8U pf[2];
                #pragma unroll
                for (int mf = 0; mf < 2; mf++) {
                    int a0 = __shfl(eh[mf][2 * kc][0],     srcA);
                    int a1 = __shfl(eh[mf][2 * kc][1],     srcA);
                    int b0 = __shfl(eh[mf][2 * kc + 1][0], srcA);
                    int b1 = __shfl(eh[mf][2 * kc + 1][1], srcA);
                    int c0 = __shfl(eh[mf][2 * kc][0],     srcB);
                    int c1 = __shfl(eh[mf][2 * kc][1],     srcB);
                    int d0 = __shfl(eh[mf][2 * kc + 1][0], srcB);
                    int d1 = __shfl(eh[mf][2 * kc + 1][1], srcB);
                    pf[mf].u[0] = hiK ? b0 : a0;
                    pf[mf].u[1] = hiK ? b1 : a1;
                    pf[mf].u[2] = hiK ? d0 : c0;
                    pf[mf].u[3] = hiK ? d1 : c1;
                }
                __builtin_amdgcn_s_setprio(1);
                #pragma unroll
                for (int nf = 0; nf < 4; nf++) {
                    int row = nf * 16 + l15;
                    int sc = ((kc * 4 + quad) ^ (row & 7));
                    half8 vf = *(const half8*)&Vs[cur][row * 64 + sc * 8];
                    o[0][nf] = __builtin_amdgcn_mfma_f32_16x16x32_f16(vf, pf[0].h, o[0][nf], 0, 0, 0);
                    o[1][nf] = __builtin_amdgcn_mfma_f32_16x16x32_f16(vf, pf[1].h, o[1][nf], 0, 0, 0);
                }
                __builtin_amdgcn_s_setprio(0);
            }
        }
    }

    // epilogue: O^T cols = queries; d = 16nf + 4quad + r -> half4 stores
    #pragma unroll
    for (int mf = 0; mf < 2; mf++) {
        float inv = 1.0f / l_i[mf];
        int s = q0 + wm + mf * 16 + l15;
        half_t* op = ctx + (size_t)(b * SEQ + s) * DOUT + h * 64 + quad * 4;
        #pragma unroll
        for (int nf = 0; nf < 4; nf++) {
            half4 hv;
            hv[0] = (half_t)(o[mf][nf][0] * inv);
            hv[1] = (half_t)(o[mf][nf][1] * inv);
            hv[2] = (half_t)(o[mf][nf][2] * inv);
            hv[3] = (half_t)(o[mf][nf][3] * inv);
            *(half4*)(op + nf * 16) = hv;
        }
    }
}

// ---------------------------------------------------------------- launch
extern "C" void kernel_launch(void* const* d_in, const int* in_sizes, int n_in,
                              void* d_out, int out_size, void* d_ws, size_t ws_size,
                              hipStream_t stream) {
    const float* x    = (const float*)d_in[0];
    const float* cosb = (const float*)d_in[1];
    const float* sinb = (const float*)d_in[2];
    const float* Wq   = (const float*)d_in[4];
    const float* Wk   = (const float*)d_in[5];
    const float* Wv   = (const float*)d_in[6];
    const float* Wo   = (const float*)d_in[7];
    float* out = (float*)d_out;

    const size_t M  = (size_t)BB * SEQ;   // 4096

    char* ws = (char*)d_ws;
    const size_t MB = 1048576;
    half_t* xh     = (half_t*)(ws);              // 16 MiB
    half_t* WqkvT  = (half_t*)(ws + 16 * MB);    // 12 MiB  [3072][2048]
    half_t* WoT    = (half_t*)(ws + 28 * MB);    //  8 MiB
    half_t* Qh     = (half_t*)(ws + 36 * MB);    // 16 MiB  [b][h][s][64] (RoPE'd + scaled)
    half_t* Kh     = (half_t*)(ws + 52 * MB);    //  4 MiB  [b][g][s][64] (RoPE'd)
    half_t* Vt     = (half_t*)(ws + 56 * MB);    //  4 MiB  [b][g][d][SEQ]
    half_t* ctxh   = (half_t*)(ws + 60 * MB);    // 16 MiB  [b][s][h*64]

    // fused cast + weight transposes (1 dispatch instead of 5)
    prep<<<18432, 256, 0, stream>>>(x, Wq, Wk, Wv, Wo, xh, WqkvT, WoT);

    // fused QKV projection + Q/K-RoPE + relayout
    gemm_qkv<<<dim3(3072 / 128, M / 128), 256, 0, stream>>>(xh, WqkvT, cosb, sinb, Qh, Kh, Vt);

    // attention
    attn<<<BB * NH * (SEQ / 128), 256, 0, stream>>>(Qh, Kh, Vt, ctxh);

    // output projection (f32 out)
    gemm_tn_f<<<dim3(DOUT / 128, M / 128), 256, 0, stream>>>(ctxh, WoT, out);
}